// Round 1
// baseline (865.643 us; speedup 1.0000x reference)
//
#include <hip/hip_runtime.h>
#include <math.h>

#define D 64

// ===================== CSR build (per call, deterministic work) =====================
__global__ void count_k(const int* __restrict__ dst, int E, int* __restrict__ deg) {
  int i = blockIdx.x * blockDim.x + threadIdx.x;
  if (i < E) atomicAdd(&deg[dst[i]], 1);
}

// single-block exclusive scan over deg[N] -> rp[N+1], cur[N] (N <= 16384)
__global__ void scan_k(const int* __restrict__ deg, int N,
                       int* __restrict__ rp, int* __restrict__ cur) {
  __shared__ int part[1024];
  int t = threadIdx.x;
  int per = (N + 1023) >> 10;
  int base = t * per;
  int local[16];
  int sum = 0;
  for (int j = 0; j < per; ++j) {
    int idx = base + j;
    int v = (idx < N) ? deg[idx] : 0;
    local[j] = sum;
    sum += v;
  }
  part[t] = sum;
  __syncthreads();
  for (int off = 1; off < 1024; off <<= 1) {
    int v = (t >= off) ? part[t - off] : 0;
    __syncthreads();
    part[t] += v;
    __syncthreads();
  }
  int coff = (t == 0) ? 0 : part[t - 1];
  for (int j = 0; j < per; ++j) {
    int idx = base + j;
    if (idx < N) { rp[idx] = coff + local[j]; cur[idx] = coff + local[j]; }
  }
  if (t == 1023) rp[N] = part[1023];
}

__global__ void scatter_k(const int* __restrict__ src, const int* __restrict__ dst,
                          int E, int* __restrict__ cur, int* __restrict__ col) {
  int i = blockIdx.x * blockDim.x + threadIdx.x;
  if (i < E) {
    int pos = atomicAdd(&cur[dst[i]], 1);
    col[pos] = src[i];
  }
}

// ===================== small GEMM: out[N,64] = concat(parts,axis=1) @ W + b =====================
// one wave handles 4 rows; lane = output column. W row-major [nparts*64, 64].
__global__ void __launch_bounds__(256) gemm_cat_k(
    const float* __restrict__ A0, const float* __restrict__ A1, const float* __restrict__ A2,
    int nparts, const float* __restrict__ W, const float* __restrict__ bias,
    float* __restrict__ out, int N)
{
  int wave = threadIdx.x >> 6, lane = threadIdx.x & 63;
  int r0 = blockIdx.x * 16 + wave * 4;
  if (r0 >= N) return;
  float bv = bias[lane];
  float acc0 = bv, acc1 = bv, acc2 = bv, acc3 = bv;
  for (int p = 0; p < nparts; ++p) {
    const float* Ap = ((p == 0) ? A0 : (p == 1) ? A1 : A2) + (size_t)r0 * D;
    const float* Wp = W + p * D * D;
#pragma unroll 8
    for (int k = 0; k < D; ++k) {
      float wv = Wp[k * D + lane];
      acc0 = fmaf(Ap[k],         wv, acc0);
      acc1 = fmaf(Ap[k + D],     wv, acc1);
      acc2 = fmaf(Ap[k + 2 * D], wv, acc2);
      acc3 = fmaf(Ap[k + 3 * D], wv, acc3);
    }
  }
  out[(size_t)r0 * D + lane]       = acc0;
  out[(size_t)(r0 + 1) * D + lane] = acc1;
  out[(size_t)(r0 + 2) * D + lane] = acc2;
  out[(size_t)(r0 + 3) * D + lane] = acc3;
}

// ===================== fused GATv2 aggregation (per-dst wave, online softmax) =====================
__global__ void __launch_bounds__(256) gat_agg_k(
    const float* __restrict__ el, const float* __restrict__ er, const float* __restrict__ a,
    const int* __restrict__ rp, const int* __restrict__ col,
    float* __restrict__ out, int Nd)
{
  int v = blockIdx.x * 4 + (threadIdx.x >> 6);
  int lane = threadIdx.x & 63;
  if (v >= Nd) return;
  int beg = rp[v], end = rp[v + 1];
  float erv = er[(size_t)v * D + lane];
  float av = a[lane];
  float m = -INFINITY, z = 0.f, acc = 0.f;
  for (int i = beg; i < end; ++i) {
    int u = col[i];
    float elu = el[(size_t)u * D + lane];
    float x = elu + erv;
    float t = (x > 0.f) ? x : 0.2f * x;   // leaky_relu slope 0.2
    float p = t * av;
#pragma unroll
    for (int o = 32; o > 0; o >>= 1) p += __shfl_xor(p, o, 64);  // s_e in all lanes
    float mn = fmaxf(m, p);
    float sc = expf(m - mn);              // m=-inf first iter -> 0
    float w  = expf(p - mn);
    z   = z * sc + w;
    acc = acc * sc + w * elu;
    m = mn;
  }
  out[(size_t)v * D + lane] = (end > beg) ? acc / z : 0.f;
}

// ===================== ChebConv propagation =====================
// mode 1: out = -re*P(xin) + xin*(re-1)
// mode 2: out = -2re*P(xin) + 2(re-1)*xin - xprev
__global__ void __launch_bounds__(256) cheb_prop_k(
    const float* __restrict__ xin, const float* __restrict__ xprev,
    const float* __restrict__ nrm, const int* __restrict__ rp, const int* __restrict__ col,
    const float* __restrict__ lambda_max, float* __restrict__ out, int N, int mode)
{
  int v = blockIdx.x * 4 + (threadIdx.x >> 6);
  int lane = threadIdx.x & 63;
  if (v >= N) return;
  float re = 2.0f / lambda_max[0];
  int beg = rp[v], end = rp[v + 1];
  float acc = 0.f;
  for (int i = beg; i < end; ++i) {
    int u = col[i];
    acc += xin[(size_t)u * D + lane] * nrm[u];
  }
  float pv = acc * nrm[v];
  float xi = xin[(size_t)v * D + lane];
  float o = (mode == 1) ? (-re * pv + xi * (re - 1.0f))
                        : (-2.0f * re * pv + 2.0f * (re - 1.0f) * xi
                           - xprev[(size_t)v * D + lane]);
  out[(size_t)v * D + lane] = o;
}

__global__ void norm_k(const int* __restrict__ rp, float* __restrict__ nrm, int N) {
  int v = blockIdx.x * blockDim.x + threadIdx.x;
  if (v < N) {
    float d = (float)(rp[v + 1] - rp[v]);
    nrm[v] = rsqrtf(fmaxf(d, 1.0f));
  }
}

// ===================== mutualistic layer (row softmax over D=64) =====================
__global__ void __launch_bounds__(256) mutual_k(
    const float* __restrict__ hP, const float* __restrict__ hS,
    float* __restrict__ mPv, float* __restrict__ mSv, int N)
{
  int v = blockIdx.x * 4 + (threadIdx.x >> 6);
  int lane = threadIdx.x & 63;
  if (v >= N) return;
  float p = hP[(size_t)v * D + lane], s = hS[(size_t)v * D + lane];
  float hm = p * s;
  float mp = p, ms = s;
#pragma unroll
  for (int o = 32; o > 0; o >>= 1) {
    mp = fmaxf(mp, __shfl_xor(mp, o, 64));
    ms = fmaxf(ms, __shfl_xor(ms, o, 64));
  }
  float ep = expf(p - mp), es = expf(s - ms);
  float zp = ep, zs = es;
#pragma unroll
  for (int o = 32; o > 0; o >>= 1) {
    zp += __shfl_xor(zp, o, 64);
    zs += __shfl_xor(zs, o, 64);
  }
  mPv[(size_t)v * D + lane] = hm * (ep / zp);
  mSv[(size_t)v * D + lane] = hm * (es / zs);
}

// ===================== C = A @ B^T, A[M,64], B[N,64], C[M,N] =====================
// 128x128 C-tile, 256 threads, 8x8 per thread, K=64 in one shot.
// LDS layout: element (r,k) at r*64 + ((k + 4*((r>>3)&7)) & 63)  -> <=2-way bank conflicts.
__global__ void __launch_bounds__(256) abt_gemm_k(
    const float* __restrict__ A, const float* __restrict__ B,
    float* __restrict__ C, int ldc)
{
  __shared__ __align__(16) float As[128 * 64];
  __shared__ __align__(16) float Bs[128 * 64];
  int t = threadIdx.x;
  size_t bi = (size_t)blockIdx.y * 128, bj = (size_t)blockIdx.x * 128;
#pragma unroll
  for (int i = 0; i < 8; ++i) {
    int fi = t + i * 256;          // float4 index 0..2047
    int r = fi >> 4;               // 16 float4 per 64-float row
    int k = (fi & 15) << 2;
    int sk = ((r >> 3) & 7) << 2;
    int idx = r * 64 + ((k + sk) & 63);
    float4 avv = *reinterpret_cast<const float4*>(A + (bi + r) * 64 + k);
    float4 bvv = *reinterpret_cast<const float4*>(B + (bj + r) * 64 + k);
    *reinterpret_cast<float4*>(&As[idx]) = avv;
    *reinterpret_cast<float4*>(&Bs[idx]) = bvv;
  }
  __syncthreads();
  int tx = t & 15, ty = t >> 4;
  int ra = ty * 8, rb = tx * 8;
  int sa = (ty & 7) << 2, sb = (tx & 7) << 2;   // row-group skews
  float c[8][8];
#pragma unroll
  for (int i = 0; i < 8; ++i)
#pragma unroll
    for (int j = 0; j < 8; ++j) c[i][j] = 0.f;

  for (int k = 0; k < 64; k += 4) {
    int kk_a = (k + sa) & 63;
    int kk_b = (k + sb) & 63;
    float4 av[8], bv[8];
#pragma unroll
    for (int i = 0; i < 8; ++i)
      av[i] = *reinterpret_cast<const float4*>(&As[(ra + i) * 64 + kk_a]);
#pragma unroll
    for (int j = 0; j < 8; ++j)
      bv[j] = *reinterpret_cast<const float4*>(&Bs[(rb + j) * 64 + kk_b]);
#pragma unroll
    for (int i = 0; i < 8; ++i)
#pragma unroll
      for (int j = 0; j < 8; ++j) {
        c[i][j] = fmaf(av[i].x, bv[j].x, c[i][j]);
        c[i][j] = fmaf(av[i].y, bv[j].y, c[i][j]);
        c[i][j] = fmaf(av[i].z, bv[j].z, c[i][j]);
        c[i][j] = fmaf(av[i].w, bv[j].w, c[i][j]);
      }
  }
#pragma unroll
  for (int i = 0; i < 8; ++i) {
    size_t row = (bi + ra + i) * (size_t)ldc + bj + rb;
    *reinterpret_cast<float4*>(&C[row])     = make_float4(c[i][0], c[i][1], c[i][2], c[i][3]);
    *reinterpret_cast<float4*>(&C[row + 4]) = make_float4(c[i][4], c[i][5], c[i][6], c[i][7]);
  }
}

// ===================== host orchestration =====================
extern "C" void kernel_launch(void* const* d_in, const int* in_sizes, int n_in,
                              void* d_out, int out_size, void* d_ws, size_t ws_size,
                              hipStream_t stream)
{
  (void)n_in; (void)out_size; (void)ws_size;
  const float* u  = (const float*)d_in[0];
  const float* it = (const float*)d_in[1];
  const float* g1r_Ws = (const float*)d_in[2];  const float* g1r_bs = (const float*)d_in[3];
  const float* g1r_Wd = (const float*)d_in[4];  const float* g1r_bd = (const float*)d_in[5];
  const float* g1r_a  = (const float*)d_in[6];
  const float* g1d_Ws = (const float*)d_in[7];  const float* g1d_bs = (const float*)d_in[8];
  const float* g1d_Wd = (const float*)d_in[9];  const float* g1d_bd = (const float*)d_in[10];
  const float* g1d_a  = (const float*)d_in[11];
  const float* g2d_Ws = (const float*)d_in[12]; const float* g2d_bs = (const float*)d_in[13];
  const float* g2d_Wd = (const float*)d_in[14]; const float* g2d_bd = (const float*)d_in[15];
  const float* g2d_a  = (const float*)d_in[16];
  const float* g2f_Ws = (const float*)d_in[17]; const float* g2f_bs = (const float*)d_in[18];
  const float* g2f_Wd = (const float*)d_in[19]; const float* g2f_bd = (const float*)d_in[20];
  const float* g2f_a  = (const float*)d_in[21];
  const float* spec_Ws = (const float*)d_in[22]; const float* spec_bs = (const float*)d_in[23];
  const float* spec_Wd = (const float*)d_in[24]; const float* spec_bd = (const float*)d_in[25];
  const float* spec_a  = (const float*)d_in[26];
  const float* cheb_W = (const float*)d_in[27]; const float* cheb_b = (const float*)d_in[28];
  const float* out_W  = (const float*)d_in[29]; const float* out_b  = (const float*)d_in[30];
  const float* mc_W   = (const float*)d_in[31]; const float* mc_b   = (const float*)d_in[32];
  const float* ms_W   = (const float*)d_in[33]; const float* ms_b   = (const float*)d_in[34];
  const float* pp_W   = (const float*)d_in[35]; const float* pp_b   = (const float*)d_in[36];
  const float* ps_W   = (const float*)d_in[37]; const float* ps_b   = (const float*)d_in[38];
  const float* lambda_max = (const float*)d_in[39];
  const int* rate_src   = (const int*)d_in[40];
  const int* rate_dst   = (const int*)d_in[41];
  const int* friend_src = (const int*)d_in[42];
  const int* friend_dst = (const int*)d_in[43];

  const int NU = in_sizes[0] / D;        // 8192
  const int NI = in_sizes[1] / D;        // 8192
  const int ER = in_sizes[40];           // 524288
  const int EF = in_sizes[42];           // 262144

  // ---- workspace carve (~20 MB) ----
  const size_t NF = (size_t)NU * D;
  float* B0 = (float*)d_ws;
  float* B1 = B0 + NF;
  float* B2 = B1 + NF;
  float* B3 = B2 + NF;
  float* B4 = B3 + NF;
  float* B5 = B4 + NF;
  float* B6 = B5 + NF;
  float* nrm = B6 + NF;                  // [NU]
  int* ip     = (int*)(nrm + NU);
  int* rp_Rd  = ip;                      // NI+1
  int* rp_Rs  = rp_Rd + (NI + 1);        // NU+1
  int* rp_Fd  = rp_Rs + (NU + 1);        // NU+1
  int* cur_Rd = rp_Fd + (NU + 1);        // NI
  int* cur_Rs = cur_Rd + NI;             // NU
  int* cur_Fd = cur_Rs + NU;             // NU
  int* col_Rd = cur_Fd + NU;             // ER
  int* col_Rs = col_Rd + ER;             // ER
  int* col_Fd = col_Rs + ER;             // EF
  int* degtmp = col_Fd + EF;             // max(NU,NI)

  dim3 b256(256);

  // ---- CSR builds: rate-by-dst, rate-by-src, friend-by-dst ----
  hipMemsetAsync(degtmp, 0, NI * sizeof(int), stream);
  count_k<<<(ER + 255) / 256, b256, 0, stream>>>(rate_dst, ER, degtmp);
  scan_k<<<1, 1024, 0, stream>>>(degtmp, NI, rp_Rd, cur_Rd);
  scatter_k<<<(ER + 255) / 256, b256, 0, stream>>>(rate_src, rate_dst, ER, cur_Rd, col_Rd);

  hipMemsetAsync(degtmp, 0, NU * sizeof(int), stream);
  count_k<<<(ER + 255) / 256, b256, 0, stream>>>(rate_src, ER, degtmp);
  scan_k<<<1, 1024, 0, stream>>>(degtmp, NU, rp_Rs, cur_Rs);
  scatter_k<<<(ER + 255) / 256, b256, 0, stream>>>(rate_dst, rate_src, ER, cur_Rs, col_Rs);

  hipMemsetAsync(degtmp, 0, NU * sizeof(int), stream);
  count_k<<<(EF + 255) / 256, b256, 0, stream>>>(friend_dst, EF, degtmp);
  scan_k<<<1, 1024, 0, stream>>>(degtmp, NU, rp_Fd, cur_Fd);
  scatter_k<<<(EF + 255) / 256, b256, 0, stream>>>(friend_src, friend_dst, EF, cur_Fd, col_Fd);

  // ---- GAT1: h1_item (B2) ----
  gemm_cat_k<<<NU / 16, b256, 0, stream>>>(u, nullptr, nullptr, 1, g1r_Ws, g1r_bs, B0, NU);
  gemm_cat_k<<<NI / 16, b256, 0, stream>>>(it, nullptr, nullptr, 1, g1r_Wd, g1r_bd, B1, NI);
  gat_agg_k<<<NI / 4, b256, 0, stream>>>(B0, B1, g1r_a, rp_Rd, col_Rd, B2, NI);
  // ---- GAT2: h2_user (B3) ----
  gemm_cat_k<<<NI / 16, b256, 0, stream>>>(it, nullptr, nullptr, 1, g1d_Ws, g1d_bs, B0, NI);
  gemm_cat_k<<<NU / 16, b256, 0, stream>>>(u, nullptr, nullptr, 1, g1d_Wd, g1d_bd, B1, NU);
  gat_agg_k<<<NU / 4, b256, 0, stream>>>(B0, B1, g1d_a, rp_Rs, col_Rs, B3, NU);
  // ---- GAT3: item_inf (B4) ----
  gemm_cat_k<<<NI / 16, b256, 0, stream>>>(B2, nullptr, nullptr, 1, g2d_Ws, g2d_bs, B0, NI);
  gemm_cat_k<<<NU / 16, b256, 0, stream>>>(u, nullptr, nullptr, 1, g2d_Wd, g2d_bd, B1, NU);
  gat_agg_k<<<NU / 4, b256, 0, stream>>>(B0, B1, g2d_a, rp_Rs, col_Rs, B4, NU);
  // ---- GAT4: social_it (B5) ----
  gemm_cat_k<<<NU / 16, b256, 0, stream>>>(B3, nullptr, nullptr, 1, g2f_Ws, g2f_bs, B0, NU);
  gemm_cat_k<<<NU / 16, b256, 0, stream>>>(u, nullptr, nullptr, 1, g2f_Wd, g2f_bd, B1, NU);
  gat_agg_k<<<NU / 4, b256, 0, stream>>>(B0, B1, g2f_a, rp_Fd, col_Fd, B5, NU);
  // ---- user_pref (B6) = [item_inf, social_it] @ out_W + out_b ----
  gemm_cat_k<<<NU / 16, b256, 0, stream>>>(B4, B5, nullptr, 2, out_W, out_b, B6, NU);

  // ---- spectral branch ----
  norm_k<<<(NU + 255) / 256, b256, 0, stream>>>(rp_Fd, nrm, NU);
  cheb_prop_k<<<NU / 4, b256, 0, stream>>>(u, nullptr, nrm, rp_Fd, col_Fd, lambda_max, B2, NU, 1); // X1
  cheb_prop_k<<<NU / 4, b256, 0, stream>>>(B2, u, nrm, rp_Fd, col_Fd, lambda_max, B3, NU, 2);      // X2
  gemm_cat_k<<<NU / 16, b256, 0, stream>>>(u, B2, B3, 3, cheb_W, cheb_b, B4, NU);                  // ch
  // ---- GAT5: user_social (B2) ----
  gemm_cat_k<<<NU / 16, b256, 0, stream>>>(B4, nullptr, nullptr, 1, spec_Ws, spec_bs, B0, NU);
  gemm_cat_k<<<NU / 16, b256, 0, stream>>>(B4, nullptr, nullptr, 1, spec_Wd, spec_bd, B1, NU);
  gat_agg_k<<<NU / 4, b256, 0, stream>>>(B0, B1, spec_a, rp_Fd, col_Fd, B2, NU);

  // ---- mutualistic + prediction ----
  gemm_cat_k<<<NU / 16, b256, 0, stream>>>(B6, u, nullptr, 2, mc_W, mc_b, B3, NU);   // h_uP
  gemm_cat_k<<<NU / 16, b256, 0, stream>>>(B2, u, nullptr, 2, ms_W, ms_b, B4, NU);   // h_uS
  mutual_k<<<NU / 4, b256, 0, stream>>>(B3, B4, B5, B6, NU);                          // h_mP=B5, h_mS=B6
  gemm_cat_k<<<NU / 16, b256, 0, stream>>>(B5, B3, nullptr, 2, pp_W, pp_b, B0, NU);  // h_new_P
  gemm_cat_k<<<NU / 16, b256, 0, stream>>>(B6, B4, nullptr, 2, ps_W, ps_b, B1, NU);  // h_new_S

  // ---- final rank-64 output GEMMs ----
  float* outf = (float*)d_out;
  abt_gemm_k<<<dim3(NI / 128, NU / 128), b256, 0, stream>>>(B0, it, outf, NI);
  abt_gemm_k<<<dim3(NU / 128, NU / 128), b256, 0, stream>>>(B1, u, outf + (size_t)NU * NI, NU);
}

// Round 2
// 655.393 us; speedup vs baseline: 1.3208x; 1.3208x over previous
//
#include <hip/hip_runtime.h>
#include <math.h>

#define D 64

typedef float f32x4 __attribute__((ext_vector_type(4)));
typedef short short8 __attribute__((ext_vector_type(8)));

// ===================== CSR build (fused, per call) =====================
__global__ void count3_k(const int* __restrict__ rate_src, const int* __restrict__ rate_dst,
                         const int* __restrict__ friend_dst, int ER, int EF,
                         int* __restrict__ degRd, int* __restrict__ degRs, int* __restrict__ degFd) {
  int i = blockIdx.x * blockDim.x + threadIdx.x;
  if (i < ER) atomicAdd(&degRd[rate_dst[i]], 1);
  else if (i < 2 * ER) atomicAdd(&degRs[rate_src[i - ER]], 1);
  else if (i < 2 * ER + EF) atomicAdd(&degFd[friend_dst[i - 2 * ER]], 1);
}

// 3 blocks, one per segment; block 2 also writes nrm = rsqrt(max(deg,1))
__global__ void scan3_k(const int* __restrict__ deg3, int NI, int NU,
                        int* __restrict__ rp_Rd, int* __restrict__ rp_Rs, int* __restrict__ rp_Fd,
                        int* __restrict__ cur_Rd, int* __restrict__ cur_Rs, int* __restrict__ cur_Fd,
                        float* __restrict__ nrm) {
  __shared__ int part[1024];
  int b = blockIdx.x, t = threadIdx.x;
  const int* deg = deg3 + ((b == 0) ? 0 : (b == 1) ? NI : NI + NU);
  int N = (b == 0) ? NI : NU;
  int* rp  = (b == 0) ? rp_Rd  : (b == 1) ? rp_Rs  : rp_Fd;
  int* cur = (b == 0) ? cur_Rd : (b == 1) ? cur_Rs : cur_Fd;
  if (b == 2) {
    for (int v = t; v < N; v += 1024) nrm[v] = rsqrtf(fmaxf((float)deg[v], 1.0f));
  }
  int per = (N + 1023) >> 10;
  int base = t * per;
  int local[16];
  int sum = 0;
  for (int j = 0; j < per; ++j) {
    int idx = base + j;
    int v = (idx < N) ? deg[idx] : 0;
    local[j] = sum;
    sum += v;
  }
  part[t] = sum;
  __syncthreads();
  for (int off = 1; off < 1024; off <<= 1) {
    int v = (t >= off) ? part[t - off] : 0;
    __syncthreads();
    part[t] += v;
    __syncthreads();
  }
  int coff = (t == 0) ? 0 : part[t - 1];
  for (int j = 0; j < per; ++j) {
    int idx = base + j;
    if (idx < N) { rp[idx] = coff + local[j]; cur[idx] = coff + local[j]; }
  }
  if (t == 1023) rp[N] = part[1023];
}

__global__ void scatter3_k(const int* __restrict__ rate_src, const int* __restrict__ rate_dst,
                           const int* __restrict__ friend_src, const int* __restrict__ friend_dst,
                           int ER, int EF,
                           int* __restrict__ cur_Rd, int* __restrict__ cur_Rs, int* __restrict__ cur_Fd,
                           int* __restrict__ col_Rd, int* __restrict__ col_Rs, int* __restrict__ col_Fd) {
  int i = blockIdx.x * blockDim.x + threadIdx.x;
  if (i < ER) {
    int pos = atomicAdd(&cur_Rd[rate_dst[i]], 1);
    col_Rd[pos] = rate_src[i];
  } else if (i < 2 * ER) {
    int j = i - ER;
    int pos = atomicAdd(&cur_Rs[rate_src[j]], 1);
    col_Rs[pos] = rate_dst[j];
  } else if (i < 2 * ER + EF) {
    int j = i - 2 * ER;
    int pos = atomicAdd(&cur_Fd[friend_dst[j]], 1);
    col_Fd[pos] = friend_src[j];
  }
}

// ===================== small GEMM: out[N,64] = concat(parts) @ W + b =====================
__device__ __forceinline__ void gemm_body(const float* A0, const float* A1, const float* A2,
                                          int nparts, const float* W, const float* bias,
                                          float* out, int N, int r0, int lane) {
  if (r0 >= N) return;
  float bv = bias[lane];
  float acc0 = bv, acc1 = bv, acc2 = bv, acc3 = bv;
  for (int p = 0; p < nparts; ++p) {
    const float* Ap = ((p == 0) ? A0 : (p == 1) ? A1 : A2) + (size_t)r0 * D;
    const float* Wp = W + p * D * D;
#pragma unroll 8
    for (int k = 0; k < D; ++k) {
      float wv = Wp[k * D + lane];
      acc0 = fmaf(Ap[k],         wv, acc0);
      acc1 = fmaf(Ap[k + D],     wv, acc1);
      acc2 = fmaf(Ap[k + 2 * D], wv, acc2);
      acc3 = fmaf(Ap[k + 3 * D], wv, acc3);
    }
  }
  out[(size_t)r0 * D + lane]       = acc0;
  out[(size_t)(r0 + 1) * D + lane] = acc1;
  out[(size_t)(r0 + 2) * D + lane] = acc2;
  out[(size_t)(r0 + 3) * D + lane] = acc3;
}

__global__ void __launch_bounds__(256) gemm_cat_k(
    const float* __restrict__ A0, const float* __restrict__ A1, const float* __restrict__ A2,
    int nparts, const float* __restrict__ W, const float* __restrict__ bias,
    float* __restrict__ out, int N) {
  int r0 = blockIdx.x * 16 + (threadIdx.x >> 6) * 4;
  gemm_body(A0, A1, A2, nparts, W, bias, out, N, r0, threadIdx.x & 63);
}

// two independent GEMMs in one launch (blockIdx.y selects)
__global__ void __launch_bounds__(256) gemm_pair_k(
    const float* A0a, const float* A1a, int npa, const float* Wa, const float* ba, float* outa, int Na,
    const float* A0b, const float* A1b, int npb, const float* Wb, const float* bb, float* outb, int Nb) {
  int r0 = blockIdx.x * 16 + (threadIdx.x >> 6) * 4;
  int lane = threadIdx.x & 63;
  if (blockIdx.y == 0) gemm_body(A0a, A1a, nullptr, npa, Wa, ba, outa, Na, r0, lane);
  else                 gemm_body(A0b, A1b, nullptr, npb, Wb, bb, outb, Nb, r0, lane);
}

// ===================== fused GATv2 aggregation =====================
// No max-subtraction (scores are O(1) here; exp(s)/sum exp(s) is exact-math identical
// to the reference's max-shifted form) -> fully associative -> 4-wide edge unroll
// with 4 independent shuffle-reduce trees to hide ds_permute latency.
__device__ __forceinline__ float lrelu02(float x) { return (x > 0.f) ? x : 0.2f * x; }

__global__ void __launch_bounds__(256) gat_agg_k(
    const float* __restrict__ el, const float* __restrict__ er, const float* __restrict__ a,
    const int* __restrict__ rp, const int* __restrict__ col,
    float* __restrict__ out, int Nd) {
  int v = blockIdx.x * 4 + (threadIdx.x >> 6);
  int lane = threadIdx.x & 63;
  if (v >= Nd) return;
  int beg = rp[v], end = rp[v + 1];
  float erv = er[(size_t)v * D + lane];
  float av = a[lane];
  float z = 0.f, acc = 0.f;
  int i = beg;
  for (; i + 4 <= end; i += 4) {
    int u0 = col[i], u1 = col[i + 1], u2 = col[i + 2], u3 = col[i + 3];
    float e0 = el[(size_t)u0 * D + lane];
    float e1 = el[(size_t)u1 * D + lane];
    float e2 = el[(size_t)u2 * D + lane];
    float e3 = el[(size_t)u3 * D + lane];
    float p0 = lrelu02(e0 + erv) * av;
    float p1 = lrelu02(e1 + erv) * av;
    float p2 = lrelu02(e2 + erv) * av;
    float p3 = lrelu02(e3 + erv) * av;
#pragma unroll
    for (int o = 32; o > 0; o >>= 1) {
      p0 += __shfl_xor(p0, o, 64);
      p1 += __shfl_xor(p1, o, 64);
      p2 += __shfl_xor(p2, o, 64);
      p3 += __shfl_xor(p3, o, 64);
    }
    float w0 = __expf(p0), w1 = __expf(p1), w2 = __expf(p2), w3 = __expf(p3);
    z += (w0 + w1) + (w2 + w3);
    acc = fmaf(w0, e0, fmaf(w1, e1, fmaf(w2, e2, fmaf(w3, e3, acc))));
  }
  for (; i < end; ++i) {
    int u = col[i];
    float e = el[(size_t)u * D + lane];
    float p = lrelu02(e + erv) * av;
#pragma unroll
    for (int o = 32; o > 0; o >>= 1) p += __shfl_xor(p, o, 64);
    float w = __expf(p);
    z += w;
    acc = fmaf(w, e, acc);
  }
  out[(size_t)v * D + lane] = (end > beg) ? acc / z : 0.f;
}

// ===================== ChebConv propagation (4-wide unrolled gather) =====================
__global__ void __launch_bounds__(256) cheb_prop_k(
    const float* __restrict__ xin, const float* __restrict__ xprev,
    const float* __restrict__ nrm, const int* __restrict__ rp, const int* __restrict__ col,
    const float* __restrict__ lambda_max, float* __restrict__ out, int N, int mode) {
  int v = blockIdx.x * 4 + (threadIdx.x >> 6);
  int lane = threadIdx.x & 63;
  if (v >= N) return;
  float re = 2.0f / lambda_max[0];
  int beg = rp[v], end = rp[v + 1];
  float acc = 0.f;
  int i = beg;
  for (; i + 4 <= end; i += 4) {
    int u0 = col[i], u1 = col[i + 1], u2 = col[i + 2], u3 = col[i + 3];
    float x0 = xin[(size_t)u0 * D + lane] * nrm[u0];
    float x1 = xin[(size_t)u1 * D + lane] * nrm[u1];
    float x2 = xin[(size_t)u2 * D + lane] * nrm[u2];
    float x3 = xin[(size_t)u3 * D + lane] * nrm[u3];
    acc += (x0 + x1) + (x2 + x3);
  }
  for (; i < end; ++i) {
    int u = col[i];
    acc += xin[(size_t)u * D + lane] * nrm[u];
  }
  float pv = acc * nrm[v];
  float xi = xin[(size_t)v * D + lane];
  float o = (mode == 1) ? (-re * pv + xi * (re - 1.0f))
                        : (-2.0f * re * pv + 2.0f * (re - 1.0f) * xi
                           - xprev[(size_t)v * D + lane]);
  out[(size_t)v * D + lane] = o;
}

// ===================== mutualistic layer =====================
__global__ void __launch_bounds__(256) mutual_k(
    const float* __restrict__ hP, const float* __restrict__ hS,
    float* __restrict__ mPv, float* __restrict__ mSv, int N) {
  int v = blockIdx.x * 4 + (threadIdx.x >> 6);
  int lane = threadIdx.x & 63;
  if (v >= N) return;
  float p = hP[(size_t)v * D + lane], s = hS[(size_t)v * D + lane];
  float hm = p * s;
  float mp = p, ms = s;
#pragma unroll
  for (int o = 32; o > 0; o >>= 1) {
    mp = fmaxf(mp, __shfl_xor(mp, o, 64));
    ms = fmaxf(ms, __shfl_xor(ms, o, 64));
  }
  float ep = __expf(p - mp), es = __expf(s - ms);
  float zp = ep, zs = es;
#pragma unroll
  for (int o = 32; o > 0; o >>= 1) {
    zp += __shfl_xor(zp, o, 64);
    zs += __shfl_xor(zs, o, 64);
  }
  mPv[(size_t)v * D + lane] = hm * (ep / zp);
  mSv[(size_t)v * D + lane] = hm * (es / zs);
}

// ===================== f32 -> bf16 hi/lo split (RNE) =====================
__device__ __forceinline__ unsigned short f2bf_rne(float x) {
  unsigned int u = __builtin_bit_cast(unsigned int, x);
  unsigned int r = u + 0x7FFFu + ((u >> 16) & 1u);
  return (unsigned short)(r >> 16);
}
__device__ __forceinline__ float bf2f(unsigned short h) {
  unsigned int u = ((unsigned int)h) << 16;
  return __builtin_bit_cast(float, u);
}

__global__ void __launch_bounds__(256) conv_split_k(
    const float* __restrict__ s0, const float* __restrict__ s1,
    const float* __restrict__ s2, const float* __restrict__ s3,
    unsigned short* __restrict__ h0, unsigned short* __restrict__ h1,
    unsigned short* __restrict__ h2, unsigned short* __restrict__ h3,
    size_t NF) {
  int m = blockIdx.y;
  const float* src = (m == 0) ? s0 : (m == 1) ? s1 : (m == 2) ? s2 : s3;
  unsigned short* hi = (m == 0) ? h0 : (m == 1) ? h1 : (m == 2) ? h2 : h3;
  unsigned short* lo = hi + NF;
  size_t i = ((size_t)blockIdx.x * 256 + threadIdx.x) * 4;
  if (i >= NF) return;
  float4 xv = *reinterpret_cast<const float4*>(src + i);
  ushort4 hv, lv;
  float x;
  x = xv.x; hv.x = f2bf_rne(x); lv.x = f2bf_rne(x - bf2f(hv.x));
  x = xv.y; hv.y = f2bf_rne(x); lv.y = f2bf_rne(x - bf2f(hv.y));
  x = xv.z; hv.z = f2bf_rne(x); lv.z = f2bf_rne(x - bf2f(hv.z));
  x = xv.w; hv.w = f2bf_rne(x); lv.w = f2bf_rne(x - bf2f(hv.w));
  *reinterpret_cast<ushort4*>(hi + i) = hv;
  *reinterpret_cast<ushort4*>(lo + i) = lv;
}

// ===================== finals: C = A @ B^T via bf16 split MFMA =====================
// A,B row-major [8192][64] as hi/lo bf16 pairs. C = Ah*Bh + Ah*Bl + Al*Bh (lo*lo dropped,
// ~2^-18 relative). Block = 128x128 C tile, 4 waves x 32 rows. Per wave: A frags held
// (8 x short8), j-tiles streamed with per-tile acc + immediate store (store-bound kernel).
__global__ void __launch_bounds__(256) mfma_abt_k(
    const unsigned short* __restrict__ Phi, const unsigned short* __restrict__ Ihi,
    const unsigned short* __restrict__ Shi, const unsigned short* __restrict__ Uhi,
    float* __restrict__ outP, float* __restrict__ outS, int ldc, size_t NF) {
  const unsigned short *Ah, *Bh;
  float* Cp;
  if (blockIdx.z == 0) { Ah = Phi; Bh = Ihi; Cp = outP; }
  else                 { Ah = Shi; Bh = Uhi; Cp = outS; }
  const unsigned short* Al = Ah + NF;
  const unsigned short* Bl = Bh + NF;

  int w = threadIdx.x >> 6, lane = threadIdx.x & 63;
  int r = lane & 15, q = lane >> 4;
  int row0 = blockIdx.y * 128 + w * 32;
  int col0 = blockIdx.x * 128;

  // A fragments: it in {0,1} (16-row subtiles), ks in {0,1} (K=32 steps)
  short8 ah00, ah01, ah10, ah11, al00, al01, al10, al11;
  {
    size_t r0 = (size_t)(row0 + r) * D;
    size_t r1 = (size_t)(row0 + 16 + r) * D;
    int ko = q * 8;
    ah00 = *reinterpret_cast<const short8*>(Ah + r0 + ko);
    ah01 = *reinterpret_cast<const short8*>(Ah + r0 + 32 + ko);
    ah10 = *reinterpret_cast<const short8*>(Ah + r1 + ko);
    ah11 = *reinterpret_cast<const short8*>(Ah + r1 + 32 + ko);
    al00 = *reinterpret_cast<const short8*>(Al + r0 + ko);
    al01 = *reinterpret_cast<const short8*>(Al + r0 + 32 + ko);
    al10 = *reinterpret_cast<const short8*>(Al + r1 + ko);
    al11 = *reinterpret_cast<const short8*>(Al + r1 + 32 + ko);
  }

  for (int jt = 0; jt < 8; ++jt) {
    size_t brow = (size_t)(col0 + jt * 16 + r) * D;
    int ko = q * 8;
    short8 bh0 = *reinterpret_cast<const short8*>(Bh + brow + ko);
    short8 bh1 = *reinterpret_cast<const short8*>(Bh + brow + 32 + ko);
    short8 bl0 = *reinterpret_cast<const short8*>(Bl + brow + ko);
    short8 bl1 = *reinterpret_cast<const short8*>(Bl + brow + 32 + ko);

    f32x4 acc0 = {0.f, 0.f, 0.f, 0.f};
    f32x4 acc1 = {0.f, 0.f, 0.f, 0.f};
    // it = 0
    acc0 = __builtin_amdgcn_mfma_f32_16x16x32_bf16(ah00, bh0, acc0, 0, 0, 0);
    acc0 = __builtin_amdgcn_mfma_f32_16x16x32_bf16(ah00, bl0, acc0, 0, 0, 0);
    acc0 = __builtin_amdgcn_mfma_f32_16x16x32_bf16(al00, bh0, acc0, 0, 0, 0);
    acc0 = __builtin_amdgcn_mfma_f32_16x16x32_bf16(ah01, bh1, acc0, 0, 0, 0);
    acc0 = __builtin_amdgcn_mfma_f32_16x16x32_bf16(ah01, bl1, acc0, 0, 0, 0);
    acc0 = __builtin_amdgcn_mfma_f32_16x16x32_bf16(al01, bh1, acc0, 0, 0, 0);
    // it = 1
    acc1 = __builtin_amdgcn_mfma_f32_16x16x32_bf16(ah10, bh0, acc1, 0, 0, 0);
    acc1 = __builtin_amdgcn_mfma_f32_16x16x32_bf16(ah10, bl0, acc1, 0, 0, 0);
    acc1 = __builtin_amdgcn_mfma_f32_16x16x32_bf16(al10, bh0, acc1, 0, 0, 0);
    acc1 = __builtin_amdgcn_mfma_f32_16x16x32_bf16(ah11, bh1, acc1, 0, 0, 0);
    acc1 = __builtin_amdgcn_mfma_f32_16x16x32_bf16(ah11, bl1, acc1, 0, 0, 0);
    acc1 = __builtin_amdgcn_mfma_f32_16x16x32_bf16(al11, bh1, acc1, 0, 0, 0);

    // C/D layout (m89): col = lane&15, row = (lane>>4)*4 + reg
    size_t cbase0 = (size_t)(row0 + q * 4) * ldc + col0 + jt * 16 + r;
    Cp[cbase0]            = acc0[0];
    Cp[cbase0 + ldc]      = acc0[1];
    Cp[cbase0 + 2 * ldc]  = acc0[2];
    Cp[cbase0 + 3 * ldc]  = acc0[3];
    size_t cbase1 = (size_t)(row0 + 16 + q * 4) * ldc + col0 + jt * 16 + r;
    Cp[cbase1]            = acc1[0];
    Cp[cbase1 + ldc]      = acc1[1];
    Cp[cbase1 + 2 * ldc]  = acc1[2];
    Cp[cbase1 + 3 * ldc]  = acc1[3];
  }
}

// ===================== host orchestration =====================
extern "C" void kernel_launch(void* const* d_in, const int* in_sizes, int n_in,
                              void* d_out, int out_size, void* d_ws, size_t ws_size,
                              hipStream_t stream) {
  (void)n_in; (void)out_size; (void)ws_size;
  const float* u  = (const float*)d_in[0];
  const float* it = (const float*)d_in[1];
  const float* g1r_Ws = (const float*)d_in[2];  const float* g1r_bs = (const float*)d_in[3];
  const float* g1r_Wd = (const float*)d_in[4];  const float* g1r_bd = (const float*)d_in[5];
  const float* g1r_a  = (const float*)d_in[6];
  const float* g1d_Ws = (const float*)d_in[7];  const float* g1d_bs = (const float*)d_in[8];
  const float* g1d_Wd = (const float*)d_in[9];  const float* g1d_bd = (const float*)d_in[10];
  const float* g1d_a  = (const float*)d_in[11];
  const float* g2d_Ws = (const float*)d_in[12]; const float* g2d_bs = (const float*)d_in[13];
  const float* g2d_Wd = (const float*)d_in[14]; const float* g2d_bd = (const float*)d_in[15];
  const float* g2d_a  = (const float*)d_in[16];
  const float* g2f_Ws = (const float*)d_in[17]; const float* g2f_bs = (const float*)d_in[18];
  const float* g2f_Wd = (const float*)d_in[19]; const float* g2f_bd = (const float*)d_in[20];
  const float* g2f_a  = (const float*)d_in[21];
  const float* spec_Ws = (const float*)d_in[22]; const float* spec_bs = (const float*)d_in[23];
  const float* spec_Wd = (const float*)d_in[24]; const float* spec_bd = (const float*)d_in[25];
  const float* spec_a  = (const float*)d_in[26];
  const float* cheb_W = (const float*)d_in[27]; const float* cheb_b = (const float*)d_in[28];
  const float* out_W  = (const float*)d_in[29]; const float* out_b  = (const float*)d_in[30];
  const float* mc_W   = (const float*)d_in[31]; const float* mc_b   = (const float*)d_in[32];
  const float* ms_W   = (const float*)d_in[33]; const float* ms_b   = (const float*)d_in[34];
  const float* pp_W   = (const float*)d_in[35]; const float* pp_b   = (const float*)d_in[36];
  const float* ps_W   = (const float*)d_in[37]; const float* ps_b   = (const float*)d_in[38];
  const float* lambda_max = (const float*)d_in[39];
  const int* rate_src   = (const int*)d_in[40];
  const int* rate_dst   = (const int*)d_in[41];
  const int* friend_src = (const int*)d_in[42];
  const int* friend_dst = (const int*)d_in[43];

  const int NU = in_sizes[0] / D;        // 8192
  const int NI = in_sizes[1] / D;        // 8192
  const int ER = in_sizes[40];           // 524288
  const int EF = in_sizes[42];           // 262144

  // ---- workspace carve ----
  const size_t NF = (size_t)NU * D;
  float* B0 = (float*)d_ws;
  float* B1 = B0 + NF;
  float* B2 = B1 + NF;
  float* B3 = B2 + NF;
  float* B4 = B3 + NF;
  float* B5 = B4 + NF;
  float* B6 = B5 + NF;
  float* nrm = B6 + NF;                  // [NU]
  int* ip     = (int*)(nrm + NU);
  int* rp_Rd  = ip;                      // NI+1
  int* rp_Rs  = rp_Rd + (NI + 1);        // NU+1
  int* rp_Fd  = rp_Rs + (NU + 1);        // NU+1
  int* cur_Rd = rp_Fd + (NU + 1);        // NI
  int* cur_Rs = cur_Rd + NI;             // NU
  int* cur_Fd = cur_Rs + NU;             // NU
  int* col_Rd = cur_Fd + NU;             // ER
  int* col_Rs = col_Rd + ER;             // ER
  int* col_Fd = col_Rs + ER;             // EF
  int* deg3   = col_Fd + EF;             // NI + NU + NU (contiguous)
  int* degRd = deg3;
  int* degRs = deg3 + NI;
  int* degFd = deg3 + NI + NU;

  // bf16 hi/lo arrays reuse B2..B5 (each B-buffer is 2 MB = hi 1 MB + lo 1 MB)
  unsigned short* Phi = (unsigned short*)B2;
  unsigned short* Ihi = (unsigned short*)B3;
  unsigned short* Shi = (unsigned short*)B4;
  unsigned short* Uhi = (unsigned short*)B5;

  dim3 b256(256);

  // ---- CSR builds (fused) ----
  hipMemsetAsync(deg3, 0, (size_t)(NI + NU + NU) * sizeof(int), stream);
  int totE = 2 * ER + EF;
  count3_k<<<(totE + 255) / 256, b256, 0, stream>>>(rate_src, rate_dst, friend_dst, ER, EF,
                                                    degRd, degRs, degFd);
  scan3_k<<<3, 1024, 0, stream>>>(deg3, NI, NU, rp_Rd, rp_Rs, rp_Fd, cur_Rd, cur_Rs, cur_Fd, nrm);
  scatter3_k<<<(totE + 255) / 256, b256, 0, stream>>>(rate_src, rate_dst, friend_src, friend_dst,
                                                      ER, EF, cur_Rd, cur_Rs, cur_Fd,
                                                      col_Rd, col_Rs, col_Fd);

  // ---- GAT1: h1_item (B2) ----
  gemm_pair_k<<<dim3(NU / 16, 2), b256, 0, stream>>>(
      u, nullptr, 1, g1r_Ws, g1r_bs, B0, NU,
      it, nullptr, 1, g1r_Wd, g1r_bd, B1, NI);
  gat_agg_k<<<NI / 4, b256, 0, stream>>>(B0, B1, g1r_a, rp_Rd, col_Rd, B2, NI);
  // ---- GAT2: h2_user (B3) ----
  gemm_pair_k<<<dim3(NU / 16, 2), b256, 0, stream>>>(
      it, nullptr, 1, g1d_Ws, g1d_bs, B0, NI,
      u, nullptr, 1, g1d_Wd, g1d_bd, B1, NU);
  gat_agg_k<<<NU / 4, b256, 0, stream>>>(B0, B1, g1d_a, rp_Rs, col_Rs, B3, NU);
  // ---- GAT3: item_inf (B4) ----
  gemm_pair_k<<<dim3(NU / 16, 2), b256, 0, stream>>>(
      B2, nullptr, 1, g2d_Ws, g2d_bs, B0, NI,
      u, nullptr, 1, g2d_Wd, g2d_bd, B1, NU);
  gat_agg_k<<<NU / 4, b256, 0, stream>>>(B0, B1, g2d_a, rp_Rs, col_Rs, B4, NU);
  // ---- GAT4: social_it (B5) ----
  gemm_pair_k<<<dim3(NU / 16, 2), b256, 0, stream>>>(
      B3, nullptr, 1, g2f_Ws, g2f_bs, B0, NU,
      u, nullptr, 1, g2f_Wd, g2f_bd, B1, NU);
  gat_agg_k<<<NU / 4, b256, 0, stream>>>(B0, B1, g2f_a, rp_Fd, col_Fd, B5, NU);
  // ---- user_pref (B6) ----
  gemm_cat_k<<<NU / 16, b256, 0, stream>>>(B4, B5, nullptr, 2, out_W, out_b, B6, NU);

  // ---- spectral branch (reuses B2,B3,B4 after GAT3/GAT4 done) ----
  cheb_prop_k<<<NU / 4, b256, 0, stream>>>(u, nullptr, nrm, rp_Fd, col_Fd, lambda_max, B2, NU, 1);
  cheb_prop_k<<<NU / 4, b256, 0, stream>>>(B2, u, nrm, rp_Fd, col_Fd, lambda_max, B3, NU, 2);
  gemm_cat_k<<<NU / 16, b256, 0, stream>>>(u, B2, B3, 3, cheb_W, cheb_b, B4, NU);
  // ---- GAT5: user_social (B2) ----
  gemm_pair_k<<<dim3(NU / 16, 2), b256, 0, stream>>>(
      B4, nullptr, 1, spec_Ws, spec_bs, B0, NU,
      B4, nullptr, 1, spec_Wd, spec_bd, B1, NU);
  gat_agg_k<<<NU / 4, b256, 0, stream>>>(B0, B1, spec_a, rp_Fd, col_Fd, B2, NU);

  // ---- mutualistic + prediction ----
  gemm_pair_k<<<dim3(NU / 16, 2), b256, 0, stream>>>(
      B6, u, 2, mc_W, mc_b, B3, NU,      // h_uP
      B2, u, 2, ms_W, ms_b, B4, NU);     // h_uS
  mutual_k<<<NU / 4, b256, 0, stream>>>(B3, B4, B5, B6, NU);  // h_mP=B5, h_mS=B6
  gemm_pair_k<<<dim3(NU / 16, 2), b256, 0, stream>>>(
      B5, B3, 2, pp_W, pp_b, B0, NU,     // h_new_P
      B6, B4, 2, ps_W, ps_b, B1, NU);    // h_new_S

  // ---- finals: split to bf16 hi/lo, then fused MFMA A@B^T ----
  conv_split_k<<<dim3((unsigned)(NF / (256 * 4)), 4), b256, 0, stream>>>(
      B0, it, B1, u, Phi, Ihi, Shi, Uhi, NF);
  float* outf = (float*)d_out;
  mfma_abt_k<<<dim3(NI / 128, NU / 128, 2), b256, 0, stream>>>(
      Phi, Ihi, Shi, Uhi, outf, outf + (size_t)NU * NI, NI, NF);
}

// Round 3
// 530.882 us; speedup vs baseline: 1.6306x; 1.2345x over previous
//
#include <hip/hip_runtime.h>
#include <math.h>

#define D 64

typedef float f32x4 __attribute__((ext_vector_type(4)));
typedef short short8 __attribute__((ext_vector_type(8)));

// ===================== DPP wave64 reductions (VALU, frees DS pipe) =====================
// butterfly: xor1 (quad_perm 1,0,3,2), xor2 (quad_perm 2,3,0,1), xor-ish4 (row_half_mirror),
// xor-ish8 (row_mirror) -> 16-group sums in all lanes; then shfl_xor 16/32 for the rest.
#define DPP_ADD(v, ctrl) \
  v += __builtin_bit_cast(float, __builtin_amdgcn_update_dpp(0, __builtin_bit_cast(int, v), ctrl, 0xF, 0xF, true))
#define DPP_MAX(v, ctrl) \
  v = fmaxf(v, __builtin_bit_cast(float, __builtin_amdgcn_update_dpp(0, __builtin_bit_cast(int, v), ctrl, 0xF, 0xF, true)))

__device__ __forceinline__ float wave_sum64(float x) {
  DPP_ADD(x, 0xB1); DPP_ADD(x, 0x4E); DPP_ADD(x, 0x141); DPP_ADD(x, 0x140);
  x += __shfl_xor(x, 16, 64);
  x += __shfl_xor(x, 32, 64);
  return x;
}
__device__ __forceinline__ float wave_max64(float x) {
  DPP_MAX(x, 0xB1); DPP_MAX(x, 0x4E); DPP_MAX(x, 0x141); DPP_MAX(x, 0x140);
  x = fmaxf(x, __shfl_xor(x, 16, 64));
  x = fmaxf(x, __shfl_xor(x, 32, 64));
  return x;
}

__device__ __forceinline__ float lrelu02(float x) { return (x > 0.f) ? x : 0.2f * x; }

// ===================== bf16 hi/lo split =====================
__device__ __forceinline__ unsigned short f2bf_rne(float x) {
  unsigned int u = __builtin_bit_cast(unsigned int, x);
  unsigned int r = u + 0x7FFFu + ((u >> 16) & 1u);
  return (unsigned short)(r >> 16);
}
__device__ __forceinline__ float bf2f(unsigned short h) {
  unsigned int u = ((unsigned int)h) << 16;
  return __builtin_bit_cast(float, u);
}

// ===================== CSR build =====================
__global__ void count3_k(const int* __restrict__ rate_src, const int* __restrict__ rate_dst,
                         const int* __restrict__ friend_dst, int ER, int EF,
                         int* __restrict__ degRd, int* __restrict__ degRs, int* __restrict__ degFd) {
  int i = blockIdx.x * blockDim.x + threadIdx.x;
  if (i < ER) atomicAdd(&degRd[rate_dst[i]], 1);
  else if (i < 2 * ER) atomicAdd(&degRs[rate_src[i - ER]], 1);
  else if (i < 2 * ER + EF) atomicAdd(&degFd[friend_dst[i - 2 * ER]], 1);
}

__global__ void scan3_k(const int* __restrict__ deg3, int NI, int NU,
                        int* __restrict__ rp_Rd, int* __restrict__ rp_Rs, int* __restrict__ rp_Fd,
                        int* __restrict__ cur_Rd, int* __restrict__ cur_Rs, int* __restrict__ cur_Fd,
                        float* __restrict__ nrm) {
  __shared__ int part[1024];
  int b = blockIdx.x, t = threadIdx.x;
  const int* deg = deg3 + ((b == 0) ? 0 : (b == 1) ? NI : NI + NU);
  int N = (b == 0) ? NI : NU;
  int* rp  = (b == 0) ? rp_Rd  : (b == 1) ? rp_Rs  : rp_Fd;
  int* cur = (b == 0) ? cur_Rd : (b == 1) ? cur_Rs : cur_Fd;
  if (b == 2) {
    for (int v = t; v < N; v += 1024) nrm[v] = rsqrtf(fmaxf((float)deg[v], 1.0f));
  }
  int per = (N + 1023) >> 10;
  int base = t * per;
  int local[16];
  int sum = 0;
  for (int j = 0; j < per; ++j) {
    int idx = base + j;
    int v = (idx < N) ? deg[idx] : 0;
    local[j] = sum;
    sum += v;
  }
  part[t] = sum;
  __syncthreads();
  for (int off = 1; off < 1024; off <<= 1) {
    int v = (t >= off) ? part[t - off] : 0;
    __syncthreads();
    part[t] += v;
    __syncthreads();
  }
  int coff = (t == 0) ? 0 : part[t - 1];
  for (int j = 0; j < per; ++j) {
    int idx = base + j;
    if (idx < N) { rp[idx] = coff + local[j]; cur[idx] = coff + local[j]; }
  }
  if (t == 1023) rp[N] = part[1023];
}

__global__ void scatter3_k(const int* __restrict__ rate_src, const int* __restrict__ rate_dst,
                           const int* __restrict__ friend_src, const int* __restrict__ friend_dst,
                           int ER, int EF,
                           int* __restrict__ cur_Rd, int* __restrict__ cur_Rs, int* __restrict__ cur_Fd,
                           int* __restrict__ col_Rd, int* __restrict__ col_Rs, int* __restrict__ col_Fd) {
  int i = blockIdx.x * blockDim.x + threadIdx.x;
  if (i < ER) {
    int pos = atomicAdd(&cur_Rd[rate_dst[i]], 1);
    col_Rd[pos] = rate_src[i];
  } else if (i < 2 * ER) {
    int j = i - ER;
    int pos = atomicAdd(&cur_Rs[rate_src[j]], 1);
    col_Rs[pos] = rate_dst[j];
  } else if (i < 2 * ER + EF) {
    int j = i - 2 * ER;
    int pos = atomicAdd(&cur_Fd[friend_dst[j]], 1);
    col_Fd[pos] = friend_src[j];
  }
}

// ===================== shared device bodies =====================
// GAT aggregation for one dst row: returns sum_e w_e*el_e / sum_e w_e (per lane = feature)
__device__ __forceinline__ float gat_row(const float* __restrict__ el, float erv, float av,
                                         const int* __restrict__ col, int beg, int end, int lane) {
  float z = 0.f, acc = 0.f;
  int i = beg;
  for (; i + 4 <= end; i += 4) {
    int u0 = col[i], u1 = col[i + 1], u2 = col[i + 2], u3 = col[i + 3];
    float e0 = el[(size_t)u0 * D + lane];
    float e1 = el[(size_t)u1 * D + lane];
    float e2 = el[(size_t)u2 * D + lane];
    float e3 = el[(size_t)u3 * D + lane];
    float p0 = wave_sum64(lrelu02(e0 + erv) * av);
    float p1 = wave_sum64(lrelu02(e1 + erv) * av);
    float p2 = wave_sum64(lrelu02(e2 + erv) * av);
    float p3 = wave_sum64(lrelu02(e3 + erv) * av);
    float w0 = __expf(p0), w1 = __expf(p1), w2 = __expf(p2), w3 = __expf(p3);
    z += (w0 + w1) + (w2 + w3);
    acc = fmaf(w0, e0, fmaf(w1, e1, fmaf(w2, e2, fmaf(w3, e3, acc))));
  }
  for (; i < end; ++i) {
    int u = col[i];
    float e = el[(size_t)u * D + lane];
    float p = wave_sum64(lrelu02(e + erv) * av);
    float w = __expf(p);
    z += w;
    acc = fmaf(w, e, acc);
  }
  return (end > beg) ? acc / z : 0.f;
}

// 4-rows-per-wave GEMM accumulate: acc[j] = b[lane] + sum_k A[r0+j][k]*W[k][lane]
__device__ __forceinline__ void gemm4(const float* A0, const float* A1, const float* A2,
                                      int nparts, const float* W, const float* bias,
                                      int r0, int lane,
                                      float& acc0, float& acc1, float& acc2, float& acc3) {
  float bv = bias[lane];
  acc0 = bv; acc1 = bv; acc2 = bv; acc3 = bv;
  for (int p = 0; p < nparts; ++p) {
    const float* Ap = ((p == 0) ? A0 : (p == 1) ? A1 : A2) + (size_t)r0 * D;
    const float* Wp = W + p * D * D;
#pragma unroll 8
    for (int k = 0; k < D; ++k) {
      float wv = Wp[k * D + lane];
      acc0 = fmaf(Ap[k],         wv, acc0);
      acc1 = fmaf(Ap[k + D],     wv, acc1);
      acc2 = fmaf(Ap[k + 2 * D], wv, acc2);
      acc3 = fmaf(Ap[k + 3 * D], wv, acc3);
    }
  }
}

// ===================== mega kernel: slice dispatch =====================
#define K_GEMM  0
#define K_GEMM2 1
#define K_GAT   2
#define K_CHEB  3
#define K_SPLIT 4

struct Slice {
  const float *a0, *a1, *a2;     // inputs (gemm parts / gat el,er / cheb xin,xprev / split src)
  const float *w, *b;            // gemm W,bias / gat a / cheb nrm,lambda_max
  const float *w2, *b2;          // GEMM2 stage-2
  const int *rp, *col;
  float *out;
  unsigned short *outh;          // SPLIT output (hi; lo at +N)
  int kind, nparts, N, nblk, mode;
};
struct Pack { Slice s[8]; };

__global__ void __launch_bounds__(256) mega_k(Pack pk, int nsl) {
  __shared__ float lds[16][D];
  int bx = blockIdx.x, si = 0;
  while (si < nsl - 1 && bx >= pk.s[si].nblk) { bx -= pk.s[si].nblk; ++si; }
  Slice S = pk.s[si];
  int w = threadIdx.x >> 6, lane = threadIdx.x & 63;

  if (S.kind == K_GEMM) {
    int r0 = __builtin_amdgcn_readfirstlane(bx * 16 + w * 4);
    float a0v, a1v, a2v, a3v;
    gemm4(S.a0, S.a1, S.a2, S.nparts, S.w, S.b, r0, lane, a0v, a1v, a2v, a3v);
    S.out[(size_t)r0 * D + lane]       = a0v;
    S.out[(size_t)(r0 + 1) * D + lane] = a1v;
    S.out[(size_t)(r0 + 2) * D + lane] = a2v;
    S.out[(size_t)(r0 + 3) * D + lane] = a3v;
  } else if (S.kind == K_GEMM2) {
    // stage 1: t = [a0,a1]@W + b  (kept in LDS); stage 2: out = [t, a2]@W2 + b2
    int r0 = __builtin_amdgcn_readfirstlane(bx * 16 + w * 4);
    float t0, t1, t2, t3;
    gemm4(S.a0, S.a1, nullptr, S.nparts, S.w, S.b, r0, lane, t0, t1, t2, t3);
    lds[w * 4 + 0][lane] = t0;
    lds[w * 4 + 1][lane] = t1;
    lds[w * 4 + 2][lane] = t2;
    lds[w * 4 + 3][lane] = t3;
    __syncthreads();
    float bv = S.b2[lane];
    float c0 = bv, c1 = bv, c2 = bv, c3 = bv;
    const float* Xp = S.a2 + (size_t)r0 * D;
#pragma unroll 8
    for (int k = 0; k < D; ++k) {
      float wv = S.w2[k * D + lane];
      c0 = fmaf(lds[w * 4 + 0][k], wv, c0);
      c1 = fmaf(lds[w * 4 + 1][k], wv, c1);
      c2 = fmaf(lds[w * 4 + 2][k], wv, c2);
      c3 = fmaf(lds[w * 4 + 3][k], wv, c3);
    }
#pragma unroll 8
    for (int k = 0; k < D; ++k) {
      float wv = S.w2[(D + k) * D + lane];
      c0 = fmaf(Xp[k],         wv, c0);
      c1 = fmaf(Xp[k + D],     wv, c1);
      c2 = fmaf(Xp[k + 2 * D], wv, c2);
      c3 = fmaf(Xp[k + 3 * D], wv, c3);
    }
    S.out[(size_t)r0 * D + lane]       = c0;
    S.out[(size_t)(r0 + 1) * D + lane] = c1;
    S.out[(size_t)(r0 + 2) * D + lane] = c2;
    S.out[(size_t)(r0 + 3) * D + lane] = c3;
  } else if (S.kind == K_GAT) {
    int v = __builtin_amdgcn_readfirstlane(bx * 4 + w);
    if (v < S.N) {
      int beg = S.rp[v], end = S.rp[v + 1];
      float erv = S.a1[(size_t)v * D + lane];
      float av = S.w[lane];
      S.out[(size_t)v * D + lane] = gat_row(S.a0, erv, av, S.col, beg, end, lane);
    }
  } else if (S.kind == K_CHEB) {
    int v = __builtin_amdgcn_readfirstlane(bx * 4 + w);
    if (v < S.N) {
      float re = 2.0f / S.b[0];
      const float* nrm = S.w;
      int beg = S.rp[v], end = S.rp[v + 1];
      float acc = 0.f;
      int i = beg;
      for (; i + 4 <= end; i += 4) {
        int u0 = S.col[i], u1 = S.col[i + 1], u2 = S.col[i + 2], u3 = S.col[i + 3];
        float x0 = S.a0[(size_t)u0 * D + lane] * nrm[u0];
        float x1 = S.a0[(size_t)u1 * D + lane] * nrm[u1];
        float x2 = S.a0[(size_t)u2 * D + lane] * nrm[u2];
        float x3 = S.a0[(size_t)u3 * D + lane] * nrm[u3];
        acc += (x0 + x1) + (x2 + x3);
      }
      for (; i < end; ++i) {
        int u = S.col[i];
        acc += S.a0[(size_t)u * D + lane] * nrm[u];
      }
      float pv = acc * nrm[v];
      float xi = S.a0[(size_t)v * D + lane];
      float o = (S.mode == 1) ? (-re * pv + xi * (re - 1.0f))
                              : (-2.0f * re * pv + 2.0f * (re - 1.0f) * xi
                                 - S.a1[(size_t)v * D + lane]);
      S.out[(size_t)v * D + lane] = o;
    }
  } else {  // K_SPLIT
    size_t i = ((size_t)bx * 256 + threadIdx.x) * 4;
    if (i < (size_t)S.N) {
      float4 xv = *reinterpret_cast<const float4*>(S.a0 + i);
      ushort4 hv, lv;
      hv.x = f2bf_rne(xv.x); lv.x = f2bf_rne(xv.x - bf2f(hv.x));
      hv.y = f2bf_rne(xv.y); lv.y = f2bf_rne(xv.y - bf2f(hv.y));
      hv.z = f2bf_rne(xv.z); lv.z = f2bf_rne(xv.z - bf2f(hv.z));
      hv.w = f2bf_rne(xv.w); lv.w = f2bf_rne(xv.w - bf2f(hv.w));
      *reinterpret_cast<ushort4*>(S.outh + i) = hv;
      *reinterpret_cast<ushort4*>(S.outh + (size_t)S.N + i) = lv;
    }
  }
}

// ===================== fused tail: GAT5 -> h_uS -> mutual -> preds -> bf16 =====================
__global__ void __launch_bounds__(256) tail_k(
    const float* __restrict__ el, const float* __restrict__ er, const float* __restrict__ a,
    const int* __restrict__ rp, const int* __restrict__ col,
    const float* __restrict__ u, const float* __restrict__ huP,
    const float* __restrict__ msW, const float* __restrict__ msb,
    const float* __restrict__ ppW, const float* __restrict__ ppb,
    const float* __restrict__ psW, const float* __restrict__ psb,
    unsigned short* __restrict__ Phl, unsigned short* __restrict__ Shl, int N) {
  __shared__ float l_us[8][D];
  __shared__ float l_mP[8][D];
  __shared__ float l_mS[8][D];
  __shared__ float l_uP[8][D];
  __shared__ float l_uS[8][D];
  const size_t NF = (size_t)N * D;
  int w = threadIdx.x >> 6, lane = threadIdx.x & 63;
  int v0 = blockIdx.x * 8;
  float av = a[lane];
  // Phase A: GAT5 aggregation (user_social), 2 dst rows per wave
#pragma unroll
  for (int j = 0; j < 2; ++j) {
    int r = w * 2 + j;
    int v = __builtin_amdgcn_readfirstlane(v0 + r);
    int beg = rp[v], end = rp[v + 1];
    float erv = er[(size_t)v * D + lane];
    l_us[r][lane] = gat_row(el, erv, av, col, beg, end, lane);
  }
  __syncthreads();
  // Phase B+C: h_uS = [us,u]@msW+msb ; mutual layer (row softmax over lane dim)
#pragma unroll
  for (int j = 0; j < 2; ++j) {
    int r = w * 2 + j;
    int v = __builtin_amdgcn_readfirstlane(v0 + r);
    const float* ur = u + (size_t)v * D;
    float acc = msb[lane];
#pragma unroll 8
    for (int k = 0; k < D; ++k) acc = fmaf(l_us[r][k], msW[k * D + lane], acc);
#pragma unroll 8
    for (int k = 0; k < D; ++k) acc = fmaf(ur[k], msW[(D + k) * D + lane], acc);
    float hS = acc;
    float hP = huP[(size_t)v * D + lane];
    float hm = hP * hS;
    float ep = __expf(hP - wave_max64(hP));
    float es = __expf(hS - wave_max64(hS));
    float mP = hm * ep / wave_sum64(ep);
    float mS = hm * es / wave_sum64(es);
    l_uP[r][lane] = hP; l_uS[r][lane] = hS;
    l_mP[r][lane] = mP; l_mS[r][lane] = mS;
  }
  __syncthreads();
  // Phase D: h_new_P = [mP,uP]@ppW+ppb, h_new_S = [mS,uS]@psW+psb -> bf16 hi/lo
#pragma unroll
  for (int j = 0; j < 2; ++j) {
    int r = w * 2 + j;
    size_t v = (size_t)(v0 + r);
    float aP = ppb[lane], aS = psb[lane];
#pragma unroll 8
    for (int k = 0; k < D; ++k) {
      aP = fmaf(l_mP[r][k], ppW[k * D + lane], aP);
      aS = fmaf(l_mS[r][k], psW[k * D + lane], aS);
    }
#pragma unroll 8
    for (int k = 0; k < D; ++k) {
      aP = fmaf(l_uP[r][k], ppW[(D + k) * D + lane], aP);
      aS = fmaf(l_uS[r][k], psW[(D + k) * D + lane], aS);
    }
    unsigned short h = f2bf_rne(aP);
    Phl[v * D + lane] = h;
    Phl[NF + v * D + lane] = f2bf_rne(aP - bf2f(h));
    h = f2bf_rne(aS);
    Shl[v * D + lane] = h;
    Shl[NF + v * D + lane] = f2bf_rne(aS - bf2f(h));
  }
}

// ===================== finals: C = A @ B^T via bf16 split MFMA =====================
__global__ void __launch_bounds__(256) mfma_abt_k(
    const unsigned short* __restrict__ Phi, const unsigned short* __restrict__ Ihi,
    const unsigned short* __restrict__ Shi, const unsigned short* __restrict__ Uhi,
    float* __restrict__ outP, float* __restrict__ outS, int ldc, size_t NF) {
  const unsigned short *Ah, *Bh;
  float* Cp;
  if (blockIdx.z == 0) { Ah = Phi; Bh = Ihi; Cp = outP; }
  else                 { Ah = Shi; Bh = Uhi; Cp = outS; }
  const unsigned short* Al = Ah + NF;
  const unsigned short* Bl = Bh + NF;

  int w = threadIdx.x >> 6, lane = threadIdx.x & 63;
  int r = lane & 15, q = lane >> 4;
  int row0 = blockIdx.y * 128 + w * 32;
  int col0 = blockIdx.x * 128;

  short8 ah00, ah01, ah10, ah11, al00, al01, al10, al11;
  {
    size_t r0 = (size_t)(row0 + r) * D;
    size_t r1 = (size_t)(row0 + 16 + r) * D;
    int ko = q * 8;
    ah00 = *reinterpret_cast<const short8*>(Ah + r0 + ko);
    ah01 = *reinterpret_cast<const short8*>(Ah + r0 + 32 + ko);
    ah10 = *reinterpret_cast<const short8*>(Ah + r1 + ko);
    ah11 = *reinterpret_cast<const short8*>(Ah + r1 + 32 + ko);
    al00 = *reinterpret_cast<const short8*>(Al + r0 + ko);
    al01 = *reinterpret_cast<const short8*>(Al + r0 + 32 + ko);
    al10 = *reinterpret_cast<const short8*>(Al + r1 + ko);
    al11 = *reinterpret_cast<const short8*>(Al + r1 + 32 + ko);
  }

  for (int jt = 0; jt < 8; ++jt) {
    size_t brow = (size_t)(col0 + jt * 16 + r) * D;
    int ko = q * 8;
    short8 bh0 = *reinterpret_cast<const short8*>(Bh + brow + ko);
    short8 bh1 = *reinterpret_cast<const short8*>(Bh + brow + 32 + ko);
    short8 bl0 = *reinterpret_cast<const short8*>(Bl + brow + ko);
    short8 bl1 = *reinterpret_cast<const short8*>(Bl + brow + 32 + ko);

    f32x4 acc0 = {0.f, 0.f, 0.f, 0.f};
    f32x4 acc1 = {0.f, 0.f, 0.f, 0.f};
    acc0 = __builtin_amdgcn_mfma_f32_16x16x32_bf16(ah00, bh0, acc0, 0, 0, 0);
    acc0 = __builtin_amdgcn_mfma_f32_16x16x32_bf16(ah00, bl0, acc0, 0, 0, 0);
    acc0 = __builtin_amdgcn_mfma_f32_16x16x32_bf16(al00, bh0, acc0, 0, 0, 0);
    acc0 = __builtin_amdgcn_mfma_f32_16x16x32_bf16(ah01, bh1, acc0, 0, 0, 0);
    acc0 = __builtin_amdgcn_mfma_f32_16x16x32_bf16(ah01, bl1, acc0, 0, 0, 0);
    acc0 = __builtin_amdgcn_mfma_f32_16x16x32_bf16(al01, bh1, acc0, 0, 0, 0);
    acc1 = __builtin_amdgcn_mfma_f32_16x16x32_bf16(ah10, bh0, acc1, 0, 0, 0);
    acc1 = __builtin_amdgcn_mfma_f32_16x16x32_bf16(ah10, bl0, acc1, 0, 0, 0);
    acc1 = __builtin_amdgcn_mfma_f32_16x16x32_bf16(al10, bh0, acc1, 0, 0, 0);
    acc1 = __builtin_amdgcn_mfma_f32_16x16x32_bf16(ah11, bh1, acc1, 0, 0, 0);
    acc1 = __builtin_amdgcn_mfma_f32_16x16x32_bf16(ah11, bl1, acc1, 0, 0, 0);
    acc1 = __builtin_amdgcn_mfma_f32_16x16x32_bf16(al11, bh1, acc1, 0, 0, 0);

    size_t cbase0 = (size_t)(row0 + q * 4) * ldc + col0 + jt * 16 + r;
    Cp[cbase0]           = acc0[0];
    Cp[cbase0 + ldc]     = acc0[1];
    Cp[cbase0 + 2 * ldc] = acc0[2];
    Cp[cbase0 + 3 * ldc] = acc0[3];
    size_t cbase1 = (size_t)(row0 + 16 + q * 4) * ldc + col0 + jt * 16 + r;
    Cp[cbase1]           = acc1[0];
    Cp[cbase1 + ldc]     = acc1[1];
    Cp[cbase1 + 2 * ldc] = acc1[2];
    Cp[cbase1 + 3 * ldc] = acc1[3];
  }
}

// ===================== host orchestration =====================
static void slice_gemm(Slice& s, const float* A0, const float* A1, const float* A2,
                       int nparts, const float* W, const float* b, float* out, int N) {
  s.kind = K_GEMM; s.a0 = A0; s.a1 = A1; s.a2 = A2; s.nparts = nparts;
  s.w = W; s.b = b; s.out = out; s.N = N; s.nblk = N / 16;
}
static void slice_gat(Slice& s, const float* el, const float* er, const float* a,
                      const int* rp, const int* col, float* out, int N) {
  s.kind = K_GAT; s.a0 = el; s.a1 = er; s.w = a; s.rp = rp; s.col = col;
  s.out = out; s.N = N; s.nblk = N / 4;
}
static void slice_cheb(Slice& s, const float* xin, const float* xprev, const float* nrm,
                       const float* lam, const int* rp, const int* col, float* out, int N, int mode) {
  s.kind = K_CHEB; s.a0 = xin; s.a1 = xprev; s.w = nrm; s.b = lam; s.rp = rp; s.col = col;
  s.out = out; s.N = N; s.nblk = N / 4; s.mode = mode;
}
static void slice_split(Slice& s, const float* src, unsigned short* outh, int nelem) {
  s.kind = K_SPLIT; s.a0 = src; s.outh = outh; s.N = nelem; s.nblk = nelem / 1024;
}
static int pack_blocks(const Pack& p, int n) {
  int t = 0;
  for (int i = 0; i < n; ++i) t += p.s[i].nblk;
  return t;
}

extern "C" void kernel_launch(void* const* d_in, const int* in_sizes, int n_in,
                              void* d_out, int out_size, void* d_ws, size_t ws_size,
                              hipStream_t stream) {
  (void)n_in; (void)out_size; (void)ws_size;
  const float* u  = (const float*)d_in[0];
  const float* it = (const float*)d_in[1];
  const float* g1r_Ws = (const float*)d_in[2];  const float* g1r_bs = (const float*)d_in[3];
  const float* g1r_Wd = (const float*)d_in[4];  const float* g1r_bd = (const float*)d_in[5];
  const float* g1r_a  = (const float*)d_in[6];
  const float* g1d_Ws = (const float*)d_in[7];  const float* g1d_bs = (const float*)d_in[8];
  const float* g1d_Wd = (const float*)d_in[9];  const float* g1d_bd = (const float*)d_in[10];
  const float* g1d_a  = (const float*)d_in[11];
  const float* g2d_Ws = (const float*)d_in[12]; const float* g2d_bs = (const float*)d_in[13];
  const float* g2d_Wd = (const float*)d_in[14]; const float* g2d_bd = (const float*)d_in[15];
  const float* g2d_a  = (const float*)d_in[16];
  const float* g2f_Ws = (const float*)d_in[17]; const float* g2f_bs = (const float*)d_in[18];
  const float* g2f_Wd = (const float*)d_in[19]; const float* g2f_bd = (const float*)d_in[20];
  const float* g2f_a  = (const float*)d_in[21];
  const float* spec_Ws = (const float*)d_in[22]; const float* spec_bs = (const float*)d_in[23];
  const float* spec_Wd = (const float*)d_in[24]; const float* spec_bd = (const float*)d_in[25];
  const float* spec_a  = (const float*)d_in[26];
  const float* cheb_W = (const float*)d_in[27]; const float* cheb_b = (const float*)d_in[28];
  const float* out_W  = (const float*)d_in[29]; const float* out_b  = (const float*)d_in[30];
  const float* mc_W   = (const float*)d_in[31]; const float* mc_b   = (const float*)d_in[32];
  const float* ms_W   = (const float*)d_in[33]; const float* ms_b   = (const float*)d_in[34];
  const float* pp_W   = (const float*)d_in[35]; const float* pp_b   = (const float*)d_in[36];
  const float* ps_W   = (const float*)d_in[37]; const float* ps_b   = (const float*)d_in[38];
  const float* lambda_max = (const float*)d_in[39];
  const int* rate_src   = (const int*)d_in[40];
  const int* rate_dst   = (const int*)d_in[41];
  const int* friend_src = (const int*)d_in[42];
  const int* friend_dst = (const int*)d_in[43];

  const int NU = in_sizes[0] / D;        // 8192
  const int NI = in_sizes[1] / D;        // 8192
  const int ER = in_sizes[40];           // 524288
  const int EF = in_sizes[42];           // 262144
  const size_t NF = (size_t)NU * D;

  // ---- workspace carve (ws ~2 GB; no aliasing, every buffer distinct) ----
  float* p = (float*)d_ws;
  float* E1 = p; p += NF;  float* R1 = p; p += NF;
  float* E2 = p; p += NF;  float* R2 = p; p += NF;
  float* E3 = p; p += NF;  float* R3 = p; p += NF;
  float* E4 = p; p += NF;  float* R4 = p; p += NF;
  float* E5 = p; p += NF;  float* R5 = p; p += NF;
  float* X1 = p; p += NF;  float* X2 = p; p += NF;
  float* H1 = p; p += NF;  float* H2 = p; p += NF;
  float* CH = p; p += NF;  float* IINF = p; p += NF;
  float* SOC = p; p += NF; float* HUP = p; p += NF;
  unsigned short* Uhl = (unsigned short*)p; p += NF;   // 2*NF ushorts = NF floats
  unsigned short* Ihl = (unsigned short*)p; p += NF;
  unsigned short* Phl = (unsigned short*)p; p += NF;
  unsigned short* Shl = (unsigned short*)p; p += NF;
  float* nrm = p; p += NU;
  int* ip     = (int*)p;
  int* rp_Rd  = ip;                      // NI+1
  int* rp_Rs  = rp_Rd + (NI + 1);        // NU+1
  int* rp_Fd  = rp_Rs + (NU + 1);        // NU+1
  int* cur_Rd = rp_Fd + (NU + 1);
  int* cur_Rs = cur_Rd + NI;
  int* cur_Fd = cur_Rs + NU;
  int* col_Rd = cur_Fd + NU;             // ER
  int* col_Rs = col_Rd + ER;             // ER
  int* col_Fd = col_Rs + ER;             // EF
  int* deg3   = col_Fd + EF;             // NI+NU+NU
  int* degRd = deg3;
  int* degRs = deg3 + NI;
  int* degFd = deg3 + NI + NU;

  dim3 b256(256);

  // ---- CSR builds ----
  hipMemsetAsync(deg3, 0, (size_t)(NI + NU + NU) * sizeof(int), stream);
  int totE = 2 * ER + EF;
  count3_k<<<(totE + 255) / 256, b256, 0, stream>>>(rate_src, rate_dst, friend_dst, ER, EF,
                                                    degRd, degRs, degFd);
  scan3_k<<<3, 1024, 0, stream>>>(deg3, NI, NU, rp_Rd, rp_Rs, rp_Fd, cur_Rd, cur_Rs, cur_Fd, nrm);
  scatter3_k<<<(totE + 255) / 256, b256, 0, stream>>>(rate_src, rate_dst, friend_src, friend_dst,
                                                      ER, EF, cur_Rd, cur_Rs, cur_Fd,
                                                      col_Rd, col_Rs, col_Fd);

  // ---- L5: layer-1 transforms + cheb X1 + u/it bf16 splits ----
  {
    Pack pk = {};
    slice_gemm(pk.s[0], u,  nullptr, nullptr, 1, g1r_Ws, g1r_bs, E1, NU);
    slice_gemm(pk.s[1], it, nullptr, nullptr, 1, g1r_Wd, g1r_bd, R1, NI);
    slice_gemm(pk.s[2], it, nullptr, nullptr, 1, g1d_Ws, g1d_bs, E2, NI);
    slice_gemm(pk.s[3], u,  nullptr, nullptr, 1, g1d_Wd, g1d_bd, R2, NU);
    slice_cheb(pk.s[4], u, nullptr, nrm, lambda_max, rp_Fd, col_Fd, X1, NU, 1);
    slice_split(pk.s[5], u,  Uhl, (int)NF);
    slice_split(pk.s[6], it, Ihl, (int)NF);
    mega_k<<<pack_blocks(pk, 7), b256, 0, stream>>>(pk, 7);
  }
  // ---- L6: GAT1 (h1_item), GAT2 (h2_user), cheb X2 ----
  {
    Pack pk = {};
    slice_gat(pk.s[0], E1, R1, g1r_a, rp_Rd, col_Rd, H1, NI);
    slice_gat(pk.s[1], E2, R2, g1d_a, rp_Rs, col_Rs, H2, NU);
    slice_cheb(pk.s[2], X1, u, nrm, lambda_max, rp_Fd, col_Fd, X2, NU, 2);
    mega_k<<<pack_blocks(pk, 3), b256, 0, stream>>>(pk, 3);
  }
  // ---- L7: layer-2 transforms + ch ----
  {
    Pack pk = {};
    slice_gemm(pk.s[0], H1, nullptr, nullptr, 1, g2d_Ws, g2d_bs, E3, NI);
    slice_gemm(pk.s[1], u,  nullptr, nullptr, 1, g2d_Wd, g2d_bd, R3, NU);
    slice_gemm(pk.s[2], H2, nullptr, nullptr, 1, g2f_Ws, g2f_bs, E4, NU);
    slice_gemm(pk.s[3], u,  nullptr, nullptr, 1, g2f_Wd, g2f_bd, R4, NU);
    slice_gemm(pk.s[4], u,  X1, X2, 3, cheb_W, cheb_b, CH, NU);
    mega_k<<<pack_blocks(pk, 5), b256, 0, stream>>>(pk, 5);
  }
  // ---- L8: GAT3 (item_inf), GAT4 (social_it) ----
  {
    Pack pk = {};
    slice_gat(pk.s[0], E3, R3, g2d_a, rp_Rs, col_Rs, IINF, NU);
    slice_gat(pk.s[1], E4, R4, g2f_a, rp_Fd, col_Fd, SOC, NU);
    mega_k<<<pack_blocks(pk, 2), b256, 0, stream>>>(pk, 2);
  }
  // ---- L9: GEMM2 user_pref->h_uP + GAT5 transforms ----
  {
    Pack pk = {};
    pk.s[0].kind = K_GEMM2;
    pk.s[0].a0 = IINF; pk.s[0].a1 = SOC; pk.s[0].nparts = 2;
    pk.s[0].w = out_W; pk.s[0].b = out_b;
    pk.s[0].a2 = u; pk.s[0].w2 = mc_W; pk.s[0].b2 = mc_b;
    pk.s[0].out = HUP; pk.s[0].N = NU; pk.s[0].nblk = NU / 16;
    slice_gemm(pk.s[1], CH, nullptr, nullptr, 1, spec_Ws, spec_bs, E5, NU);
    slice_gemm(pk.s[2], CH, nullptr, nullptr, 1, spec_Wd, spec_bd, R5, NU);
    mega_k<<<pack_blocks(pk, 3), b256, 0, stream>>>(pk, 3);
  }
  // ---- L10: fused tail ----
  tail_k<<<NU / 8, b256, 0, stream>>>(E5, R5, spec_a, rp_Fd, col_Fd, u, HUP,
                                      ms_W, ms_b, pp_W, pp_b, ps_W, ps_b, Phl, Shl, NU);
  // ---- L11: finals ----
  float* outf = (float*)d_out;
  mfma_abt_k<<<dim3(NI / 128, NU / 128, 2), b256, 0, stream>>>(
      Phl, Ihl, Shl, Uhl, outf, outf + (size_t)NU * NI, NI, NF);
}

// Round 4
// 516.403 us; speedup vs baseline: 1.6763x; 1.0280x over previous
//
#include <hip/hip_runtime.h>
#include <math.h>

#define D 64

typedef float f32x4 __attribute__((ext_vector_type(4)));
typedef short short8 __attribute__((ext_vector_type(8)));

// ===================== DPP reductions =====================
#define DPP_ADD(v, ctrl) \
  v += __builtin_bit_cast(float, __builtin_amdgcn_update_dpp(0, __builtin_bit_cast(int, v), ctrl, 0xF, 0xF, true))
#define DPP_MAX(v, ctrl) \
  v = fmaxf(v, __builtin_bit_cast(float, __builtin_amdgcn_update_dpp(0, __builtin_bit_cast(int, v), ctrl, 0xF, 0xF, true)))

// sum over each 16-lane row (result in all 16 lanes)
__device__ __forceinline__ float red16_sum(float x) {
  DPP_ADD(x, 0xB1);   // xor1 (quad_perm 1,0,3,2)
  DPP_ADD(x, 0x4E);   // xor2 (quad_perm 2,3,0,1)
  DPP_ADD(x, 0x141);  // row_half_mirror -> xor4 on quad-equal data
  DPP_ADD(x, 0x140);  // row_mirror -> xor8 on 8-equal data
  return x;
}
__device__ __forceinline__ float wave_sum64(float x) {
  x = red16_sum(x);
  x += __shfl_xor(x, 16, 64);
  x += __shfl_xor(x, 32, 64);
  return x;
}
__device__ __forceinline__ float wave_max64(float x) {
  DPP_MAX(x, 0xB1); DPP_MAX(x, 0x4E); DPP_MAX(x, 0x141); DPP_MAX(x, 0x140);
  x = fmaxf(x, __shfl_xor(x, 16, 64));
  x = fmaxf(x, __shfl_xor(x, 32, 64));
  return x;
}

__device__ __forceinline__ float lrelu02(float x) { return (x > 0.f) ? x : 0.2f * x; }

// ===================== bf16 hi/lo split =====================
__device__ __forceinline__ unsigned short f2bf_rne(float x) {
  unsigned int u = __builtin_bit_cast(unsigned int, x);
  unsigned int r = u + 0x7FFFu + ((u >> 16) & 1u);
  return (unsigned short)(r >> 16);
}
__device__ __forceinline__ float bf2f(unsigned short h) {
  unsigned int u = ((unsigned int)h) << 16;
  return __builtin_bit_cast(float, u);
}

// ===================== CSR build =====================
__global__ void count3_k(const int* __restrict__ rate_src, const int* __restrict__ rate_dst,
                         const int* __restrict__ friend_dst, int ER, int EF,
                         int* __restrict__ degRd, int* __restrict__ degRs, int* __restrict__ degFd) {
  int i = blockIdx.x * blockDim.x + threadIdx.x;
  if (i < ER) atomicAdd(&degRd[rate_dst[i]], 1);
  else if (i < 2 * ER) atomicAdd(&degRs[rate_src[i - ER]], 1);
  else if (i < 2 * ER + EF) atomicAdd(&degFd[friend_dst[i - 2 * ER]], 1);
}

__global__ void scan3_k(const int* __restrict__ deg3, int NI, int NU,
                        int* __restrict__ rp_Rd, int* __restrict__ rp_Rs, int* __restrict__ rp_Fd,
                        int* __restrict__ cur_Rd, int* __restrict__ cur_Rs, int* __restrict__ cur_Fd,
                        float* __restrict__ nrm) {
  __shared__ int part[1024];
  int b = blockIdx.x, t = threadIdx.x;
  const int* deg = deg3 + ((b == 0) ? 0 : (b == 1) ? NI : NI + NU);
  int N = (b == 0) ? NI : NU;
  int* rp  = (b == 0) ? rp_Rd  : (b == 1) ? rp_Rs  : rp_Fd;
  int* cur = (b == 0) ? cur_Rd : (b == 1) ? cur_Rs : cur_Fd;
  if (b == 2) {
    for (int v = t; v < N; v += 1024) nrm[v] = rsqrtf(fmaxf((float)deg[v], 1.0f));
  }
  int per = (N + 1023) >> 10;
  int base = t * per;
  int local[16];
  int sum = 0;
  for (int j = 0; j < per; ++j) {
    int idx = base + j;
    int v = (idx < N) ? deg[idx] : 0;
    local[j] = sum;
    sum += v;
  }
  part[t] = sum;
  __syncthreads();
  for (int off = 1; off < 1024; off <<= 1) {
    int v = (t >= off) ? part[t - off] : 0;
    __syncthreads();
    part[t] += v;
    __syncthreads();
  }
  int coff = (t == 0) ? 0 : part[t - 1];
  for (int j = 0; j < per; ++j) {
    int idx = base + j;
    if (idx < N) { rp[idx] = coff + local[j]; cur[idx] = coff + local[j]; }
  }
  if (t == 1023) rp[N] = part[1023];
}

// ===================== GAT row: 16-lane x float4 edge groups =====================
// lane = 16*g + h. Each loop iter handles 8 edges (2 guarded groups of 4).
// Returns final alpha-weighted mean for features [off, off+4) in ALL lanes.
__device__ __forceinline__ f32x4 gat_row4(const float* __restrict__ el,
                                          f32x4 er4, f32x4 a4,
                                          const int* __restrict__ col,
                                          int beg, int end, int g, int off) {
  f32x4 acc = {0.f, 0.f, 0.f, 0.f};
  float z = 0.f;
  for (int i = beg; i < end; i += 8) {
    bool act0 = (i + g) < end;
    bool act1 = (i + 4 + g) < end;
    int u0 = act0 ? col[i + g] : col[beg];
    int u1 = act1 ? col[i + 4 + g] : col[beg];
    f32x4 e0 = *reinterpret_cast<const f32x4*>(el + (size_t)u0 * D + off);
    f32x4 e1 = *reinterpret_cast<const f32x4*>(el + (size_t)u1 * D + off);
    float p0 = a4.x * lrelu02(e0.x + er4.x);
    p0 = fmaf(a4.y, lrelu02(e0.y + er4.y), p0);
    p0 = fmaf(a4.z, lrelu02(e0.z + er4.z), p0);
    p0 = fmaf(a4.w, lrelu02(e0.w + er4.w), p0);
    float p1 = a4.x * lrelu02(e1.x + er4.x);
    p1 = fmaf(a4.y, lrelu02(e1.y + er4.y), p1);
    p1 = fmaf(a4.z, lrelu02(e1.z + er4.z), p1);
    p1 = fmaf(a4.w, lrelu02(e1.w + er4.w), p1);
    p0 = red16_sum(p0);
    p1 = red16_sum(p1);
    float w0 = act0 ? __expf(p0) : 0.f;
    float w1 = act1 ? __expf(p1) : 0.f;
    z += w0 + w1;
    acc.x = fmaf(w0, e0.x, acc.x); acc.x = fmaf(w1, e1.x, acc.x);
    acc.y = fmaf(w0, e0.y, acc.y); acc.y = fmaf(w1, e1.y, acc.y);
    acc.z = fmaf(w0, e0.z, acc.z); acc.z = fmaf(w1, e1.z, acc.z);
    acc.w = fmaf(w0, e0.w, acc.w); acc.w = fmaf(w1, e1.w, acc.w);
  }
  // cross-group combine (once per row)
  acc.x += __shfl_xor(acc.x, 16, 64); acc.x += __shfl_xor(acc.x, 32, 64);
  acc.y += __shfl_xor(acc.y, 16, 64); acc.y += __shfl_xor(acc.y, 32, 64);
  acc.z += __shfl_xor(acc.z, 16, 64); acc.z += __shfl_xor(acc.z, 32, 64);
  acc.w += __shfl_xor(acc.w, 16, 64); acc.w += __shfl_xor(acc.w, 32, 64);
  z += __shfl_xor(z, 16, 64); z += __shfl_xor(z, 32, 64);
  f32x4 res;
  if (end > beg) {
    res.x = acc.x / z; res.y = acc.y / z; res.z = acc.z / z; res.w = acc.w / z;
  } else {
    res = f32x4{0.f, 0.f, 0.f, 0.f};
  }
  return res;
}

// 4-rows-per-wave GEMM accumulate (lane = output feature)
__device__ __forceinline__ void gemm4(const float* A0, const float* A1, const float* A2,
                                      int nparts, const float* W, const float* bias,
                                      int r0, int lane,
                                      float& acc0, float& acc1, float& acc2, float& acc3) {
  float bv = bias[lane];
  acc0 = bv; acc1 = bv; acc2 = bv; acc3 = bv;
  for (int p = 0; p < nparts; ++p) {
    const float* Ap = ((p == 0) ? A0 : (p == 1) ? A1 : A2) + (size_t)r0 * D;
    const float* Wp = W + p * D * D;
#pragma unroll 8
    for (int k = 0; k < D; ++k) {
      float wv = Wp[k * D + lane];
      acc0 = fmaf(Ap[k],         wv, acc0);
      acc1 = fmaf(Ap[k + D],     wv, acc1);
      acc2 = fmaf(Ap[k + 2 * D], wv, acc2);
      acc3 = fmaf(Ap[k + 3 * D], wv, acc3);
    }
  }
}

// ===================== mega kernel: slice dispatch =====================
#define K_GEMM  0
#define K_GEMM2 1
#define K_GAT   2
#define K_CHEB  3
#define K_SPLIT 4
#define K_SCAT  5

struct Slice {
  const float *a0, *a1, *a2;
  const float *w, *b;
  const float *w2, *b2;
  const int *rp, *col;
  float *out;
  unsigned short *outh;
  int kind, nparts, N, nblk, mode;
};
struct Pack { Slice s[10]; };

__global__ void __launch_bounds__(256) mega_k(Pack pk, int nsl) {
  __shared__ float lds[16][D];
  int bx = blockIdx.x, si = 0;
  while (si < nsl - 1 && bx >= pk.s[si].nblk) { bx -= pk.s[si].nblk; ++si; }
  Slice S = pk.s[si];
  int w = threadIdx.x >> 6, lane = threadIdx.x & 63;
  int g = lane >> 4, off = (lane & 15) << 2;

  if (S.kind == K_GEMM) {
    int r0 = __builtin_amdgcn_readfirstlane(bx * 16 + w * 4);
    float a0v, a1v, a2v, a3v;
    gemm4(S.a0, S.a1, S.a2, S.nparts, S.w, S.b, r0, lane, a0v, a1v, a2v, a3v);
    S.out[(size_t)r0 * D + lane]       = a0v;
    S.out[(size_t)(r0 + 1) * D + lane] = a1v;
    S.out[(size_t)(r0 + 2) * D + lane] = a2v;
    S.out[(size_t)(r0 + 3) * D + lane] = a3v;
  } else if (S.kind == K_GEMM2) {
    int r0 = __builtin_amdgcn_readfirstlane(bx * 16 + w * 4);
    float t0, t1, t2, t3;
    gemm4(S.a0, S.a1, nullptr, S.nparts, S.w, S.b, r0, lane, t0, t1, t2, t3);
    lds[w * 4 + 0][lane] = t0;
    lds[w * 4 + 1][lane] = t1;
    lds[w * 4 + 2][lane] = t2;
    lds[w * 4 + 3][lane] = t3;
    __syncthreads();
    float bv = S.b2[lane];
    float c0 = bv, c1 = bv, c2 = bv, c3 = bv;
    const float* Xp = S.a2 + (size_t)r0 * D;
#pragma unroll 8
    for (int k = 0; k < D; ++k) {
      float wv = S.w2[k * D + lane];
      c0 = fmaf(lds[w * 4 + 0][k], wv, c0);
      c1 = fmaf(lds[w * 4 + 1][k], wv, c1);
      c2 = fmaf(lds[w * 4 + 2][k], wv, c2);
      c3 = fmaf(lds[w * 4 + 3][k], wv, c3);
    }
#pragma unroll 8
    for (int k = 0; k < D; ++k) {
      float wv = S.w2[(D + k) * D + lane];
      c0 = fmaf(Xp[k],         wv, c0);
      c1 = fmaf(Xp[k + D],     wv, c1);
      c2 = fmaf(Xp[k + 2 * D], wv, c2);
      c3 = fmaf(Xp[k + 3 * D], wv, c3);
    }
    S.out[(size_t)r0 * D + lane]       = c0;
    S.out[(size_t)(r0 + 1) * D + lane] = c1;
    S.out[(size_t)(r0 + 2) * D + lane] = c2;
    S.out[(size_t)(r0 + 3) * D + lane] = c3;
  } else if (S.kind == K_GAT) {
    int v = __builtin_amdgcn_readfirstlane(bx * 4 + w);
    if (v < S.N) {
      int beg = S.rp[v], end = S.rp[v + 1];
      f32x4 er4 = *reinterpret_cast<const f32x4*>(S.a1 + (size_t)v * D + off);
      f32x4 a4  = *reinterpret_cast<const f32x4*>(S.w + off);
      f32x4 res = gat_row4(S.a0, er4, a4, S.col, beg, end, g, off);
      if (g == 0) *reinterpret_cast<f32x4*>(S.out + (size_t)v * D + off) = res;
    }
  } else if (S.kind == K_CHEB) {
    int v = __builtin_amdgcn_readfirstlane(bx * 4 + w);
    if (v < S.N) {
      float re = 2.0f / S.b[0];
      const float* nrm = S.w;
      int beg = S.rp[v], end = S.rp[v + 1];
      f32x4 acc = {0.f, 0.f, 0.f, 0.f};
      for (int i = beg; i < end; i += 8) {
        bool act0 = (i + g) < end;
        bool act1 = (i + 4 + g) < end;
        int u0 = act0 ? S.col[i + g] : S.col[beg];
        int u1 = act1 ? S.col[i + 4 + g] : S.col[beg];
        float n0 = act0 ? nrm[u0] : 0.f;
        float n1 = act1 ? nrm[u1] : 0.f;
        f32x4 e0 = *reinterpret_cast<const f32x4*>(S.a0 + (size_t)u0 * D + off);
        f32x4 e1 = *reinterpret_cast<const f32x4*>(S.a0 + (size_t)u1 * D + off);
        acc.x = fmaf(n0, e0.x, acc.x); acc.x = fmaf(n1, e1.x, acc.x);
        acc.y = fmaf(n0, e0.y, acc.y); acc.y = fmaf(n1, e1.y, acc.y);
        acc.z = fmaf(n0, e0.z, acc.z); acc.z = fmaf(n1, e1.z, acc.z);
        acc.w = fmaf(n0, e0.w, acc.w); acc.w = fmaf(n1, e1.w, acc.w);
      }
      acc.x += __shfl_xor(acc.x, 16, 64); acc.x += __shfl_xor(acc.x, 32, 64);
      acc.y += __shfl_xor(acc.y, 16, 64); acc.y += __shfl_xor(acc.y, 32, 64);
      acc.z += __shfl_xor(acc.z, 16, 64); acc.z += __shfl_xor(acc.z, 32, 64);
      acc.w += __shfl_xor(acc.w, 16, 64); acc.w += __shfl_xor(acc.w, 32, 64);
      if (g == 0) {
        float nv = nrm[v];
        f32x4 xi = *reinterpret_cast<const f32x4*>(S.a0 + (size_t)v * D + off);
        f32x4 o;
        if (S.mode == 1) {
          o.x = -re * (acc.x * nv) + xi.x * (re - 1.0f);
          o.y = -re * (acc.y * nv) + xi.y * (re - 1.0f);
          o.z = -re * (acc.z * nv) + xi.z * (re - 1.0f);
          o.w = -re * (acc.w * nv) + xi.w * (re - 1.0f);
        } else {
          f32x4 xp = *reinterpret_cast<const f32x4*>(S.a1 + (size_t)v * D + off);
          o.x = -2.0f * re * (acc.x * nv) + 2.0f * (re - 1.0f) * xi.x - xp.x;
          o.y = -2.0f * re * (acc.y * nv) + 2.0f * (re - 1.0f) * xi.y - xp.y;
          o.z = -2.0f * re * (acc.z * nv) + 2.0f * (re - 1.0f) * xi.z - xp.z;
          o.w = -2.0f * re * (acc.w * nv) + 2.0f * (re - 1.0f) * xi.w - xp.w;
        }
        *reinterpret_cast<f32x4*>(S.out + (size_t)v * D + off) = o;
      }
    }
  } else if (S.kind == K_SPLIT) {
    size_t i = ((size_t)bx * 256 + threadIdx.x) * 4;
    if (i < (size_t)S.N) {
      float4 xv = *reinterpret_cast<const float4*>(S.a0 + i);
      ushort4 hv, lv;
      hv.x = f2bf_rne(xv.x); lv.x = f2bf_rne(xv.x - bf2f(hv.x));
      hv.y = f2bf_rne(xv.y); lv.y = f2bf_rne(xv.y - bf2f(hv.y));
      hv.z = f2bf_rne(xv.z); lv.z = f2bf_rne(xv.z - bf2f(hv.z));
      hv.w = f2bf_rne(xv.w); lv.w = f2bf_rne(xv.w - bf2f(hv.w));
      *reinterpret_cast<ushort4*>(S.outh + i) = hv;
      *reinterpret_cast<ushort4*>(S.outh + (size_t)S.N + i) = lv;
    }
  } else {  // K_SCAT: rp = dst array, col = src array, out = cur (int*), outh = col_out (int*)
    int i = bx * 256 + threadIdx.x;
    if (i < S.N) {
      int d = S.rp[i];
      int pos = atomicAdd(reinterpret_cast<int*>(S.out) + d, 1);
      reinterpret_cast<int*>(S.outh)[pos] = S.col[i];
    }
  }
}

// ===================== fused tail: GAT5 -> h_uS -> mutual -> preds -> bf16 =====================
__global__ void __launch_bounds__(256) tail_k(
    const float* __restrict__ el, const float* __restrict__ er, const float* __restrict__ a,
    const int* __restrict__ rp, const int* __restrict__ col,
    const float* __restrict__ u, const float* __restrict__ huP,
    const float* __restrict__ msW, const float* __restrict__ msb,
    const float* __restrict__ ppW, const float* __restrict__ ppb,
    const float* __restrict__ psW, const float* __restrict__ psb,
    unsigned short* __restrict__ Phl, unsigned short* __restrict__ Shl, int N) {
  __shared__ float l_us[8][D];
  __shared__ float l_mP[8][D];
  __shared__ float l_mS[8][D];
  __shared__ float l_uP[8][D];
  __shared__ float l_uS[8][D];
  const size_t NF = (size_t)N * D;
  int w = threadIdx.x >> 6, lane = threadIdx.x & 63;
  int g = lane >> 4, off = (lane & 15) << 2;
  int v0 = blockIdx.x * 8;
  f32x4 a4 = *reinterpret_cast<const f32x4*>(a + off);
  // Phase A: GAT5 aggregation (user_social), 2 dst rows per wave
#pragma unroll
  for (int j = 0; j < 2; ++j) {
    int r = w * 2 + j;
    int v = __builtin_amdgcn_readfirstlane(v0 + r);
    int beg = rp[v], end = rp[v + 1];
    f32x4 er4 = *reinterpret_cast<const f32x4*>(er + (size_t)v * D + off);
    f32x4 res = gat_row4(el, er4, a4, col, beg, end, g, off);
    if (g == 0) *reinterpret_cast<f32x4*>(&l_us[r][off]) = res;
  }
  __syncthreads();
  // Phase B+C: h_uS = [us,u]@msW+msb ; mutual layer
#pragma unroll
  for (int j = 0; j < 2; ++j) {
    int r = w * 2 + j;
    int v = __builtin_amdgcn_readfirstlane(v0 + r);
    const float* ur = u + (size_t)v * D;
    float acc = msb[lane];
#pragma unroll 8
    for (int k = 0; k < D; ++k) acc = fmaf(l_us[r][k], msW[k * D + lane], acc);
#pragma unroll 8
    for (int k = 0; k < D; ++k) acc = fmaf(ur[k], msW[(D + k) * D + lane], acc);
    float hS = acc;
    float hP = huP[(size_t)v * D + lane];
    float hm = hP * hS;
    float ep = __expf(hP - wave_max64(hP));
    float es = __expf(hS - wave_max64(hS));
    float mP = hm * ep / wave_sum64(ep);
    float mS = hm * es / wave_sum64(es);
    l_uP[r][lane] = hP; l_uS[r][lane] = hS;
    l_mP[r][lane] = mP; l_mS[r][lane] = mS;
  }
  __syncthreads();
  // Phase D: h_new_P/S -> bf16 hi/lo
#pragma unroll
  for (int j = 0; j < 2; ++j) {
    int r = w * 2 + j;
    size_t v = (size_t)(v0 + r);
    float aP = ppb[lane], aS = psb[lane];
#pragma unroll 8
    for (int k = 0; k < D; ++k) {
      aP = fmaf(l_mP[r][k], ppW[k * D + lane], aP);
      aS = fmaf(l_mS[r][k], psW[k * D + lane], aS);
    }
#pragma unroll 8
    for (int k = 0; k < D; ++k) {
      aP = fmaf(l_uP[r][k], ppW[(D + k) * D + lane], aP);
      aS = fmaf(l_uS[r][k], psW[(D + k) * D + lane], aS);
    }
    unsigned short h = f2bf_rne(aP);
    Phl[v * D + lane] = h;
    Phl[NF + v * D + lane] = f2bf_rne(aP - bf2f(h));
    h = f2bf_rne(aS);
    Shl[v * D + lane] = h;
    Shl[NF + v * D + lane] = f2bf_rne(aS - bf2f(h));
  }
}

// ===================== finals: C = A @ B^T via bf16 split MFMA (operand-swapped) =====================
// Swapped operands: D = mfma(B_frag, A_frag) -> lane (r,q) reg j holds C[row0+r][col0+jt*16+q*4+j]
// -> one float4 store per sub-tile per lane (4x fewer store instrs).
__global__ void __launch_bounds__(256) mfma_abt_k(
    const unsigned short* __restrict__ Phi, const unsigned short* __restrict__ Ihi,
    const unsigned short* __restrict__ Shi, const unsigned short* __restrict__ Uhi,
    float* __restrict__ outP, float* __restrict__ outS, int ldc, size_t NF) {
  const unsigned short *Ah, *Bh;
  float* Cp;
  if (blockIdx.z == 0) { Ah = Phi; Bh = Ihi; Cp = outP; }
  else                 { Ah = Shi; Bh = Uhi; Cp = outS; }
  const unsigned short* Al = Ah + NF;
  const unsigned short* Bl = Bh + NF;

  // bijective XCD swizzle within the z-plane (nwg = 4096, %8 == 0)
  int nwg = gridDim.x * gridDim.y;
  int lin = blockIdx.y * gridDim.x + blockIdx.x;
  int cpx = nwg >> 3;
  int swz = (lin & 7) * cpx + (lin >> 3);
  int bxx = swz % gridDim.x;
  int byy = swz / gridDim.x;

  int w = threadIdx.x >> 6, lane = threadIdx.x & 63;
  int r = lane & 15, q = lane >> 4;
  int row0 = byy * 128 + w * 32;
  int col0 = bxx * 128;

  short8 ah00, ah01, ah10, ah11, al00, al01, al10, al11;
  {
    size_t r0 = (size_t)(row0 + r) * D;
    size_t r1 = (size_t)(row0 + 16 + r) * D;
    int ko = q * 8;
    ah00 = *reinterpret_cast<const short8*>(Ah + r0 + ko);
    ah01 = *reinterpret_cast<const short8*>(Ah + r0 + 32 + ko);
    ah10 = *reinterpret_cast<const short8*>(Ah + r1 + ko);
    ah11 = *reinterpret_cast<const short8*>(Ah + r1 + 32 + ko);
    al00 = *reinterpret_cast<const short8*>(Al + r0 + ko);
    al01 = *reinterpret_cast<const short8*>(Al + r0 + 32 + ko);
    al10 = *reinterpret_cast<const short8*>(Al + r1 + ko);
    al11 = *reinterpret_cast<const short8*>(Al + r1 + 32 + ko);
  }

  for (int jt = 0; jt < 8; ++jt) {
    size_t brow = (size_t)(col0 + jt * 16 + r) * D;
    int ko = q * 8;
    short8 bh0 = *reinterpret_cast<const short8*>(Bh + brow + ko);
    short8 bh1 = *reinterpret_cast<const short8*>(Bh + brow + 32 + ko);
    short8 bl0 = *reinterpret_cast<const short8*>(Bl + brow + ko);
    short8 bl1 = *reinterpret_cast<const short8*>(Bl + brow + 32 + ko);

    f32x4 acc0 = {0.f, 0.f, 0.f, 0.f};
    f32x4 acc1 = {0.f, 0.f, 0.f, 0.f};
    acc0 = __builtin_amdgcn_mfma_f32_16x16x32_bf16(bh0, ah00, acc0, 0, 0, 0);
    acc0 = __builtin_amdgcn_mfma_f32_16x16x32_bf16(bl0, ah00, acc0, 0, 0, 0);
    acc0 = __builtin_amdgcn_mfma_f32_16x16x32_bf16(bh0, al00, acc0, 0, 0, 0);
    acc0 = __builtin_amdgcn_mfma_f32_16x16x32_bf16(bh1, ah01, acc0, 0, 0, 0);
    acc0 = __builtin_amdgcn_mfma_f32_16x16x32_bf16(bl1, ah01, acc0, 0, 0, 0);
    acc0 = __builtin_amdgcn_mfma_f32_16x16x32_bf16(bh1, al01, acc0, 0, 0, 0);
    acc1 = __builtin_amdgcn_mfma_f32_16x16x32_bf16(bh0, ah10, acc1, 0, 0, 0);
    acc1 = __builtin_amdgcn_mfma_f32_16x16x32_bf16(bl0, ah10, acc1, 0, 0, 0);
    acc1 = __builtin_amdgcn_mfma_f32_16x16x32_bf16(bh0, al10, acc1, 0, 0, 0);
    acc1 = __builtin_amdgcn_mfma_f32_16x16x32_bf16(bh1, ah11, acc1, 0, 0, 0);
    acc1 = __builtin_amdgcn_mfma_f32_16x16x32_bf16(bl1, ah11, acc1, 0, 0, 0);
    acc1 = __builtin_amdgcn_mfma_f32_16x16x32_bf16(bh1, al11, acc1, 0, 0, 0);

    *reinterpret_cast<f32x4*>(&Cp[(size_t)(row0 + r) * ldc + col0 + jt * 16 + q * 4])      = acc0;
    *reinterpret_cast<f32x4*>(&Cp[(size_t)(row0 + 16 + r) * ldc + col0 + jt * 16 + q * 4]) = acc1;
  }
}

// ===================== host orchestration =====================
static void slice_gemm(Slice& s, const float* A0, const float* A1, const float* A2,
                       int nparts, const float* W, const float* b, float* out, int N) {
  s.kind = K_GEMM; s.a0 = A0; s.a1 = A1; s.a2 = A2; s.nparts = nparts;
  s.w = W; s.b = b; s.out = out; s.N = N; s.nblk = N / 16;
}
static void slice_gat(Slice& s, const float* el, const float* er, const float* a,
                      const int* rp, const int* col, float* out, int N) {
  s.kind = K_GAT; s.a0 = el; s.a1 = er; s.w = a; s.rp = rp; s.col = col;
  s.out = out; s.N = N; s.nblk = N / 4;
}
static void slice_cheb(Slice& s, const float* xin, const float* xprev, const float* nrm,
                       const float* lam, const int* rp, const int* col, float* out, int N, int mode) {
  s.kind = K_CHEB; s.a0 = xin; s.a1 = xprev; s.w = nrm; s.b = lam; s.rp = rp; s.col = col;
  s.out = out; s.N = N; s.nblk = N / 4; s.mode = mode;
}
static void slice_split(Slice& s, const float* src, unsigned short* outh, int nelem) {
  s.kind = K_SPLIT; s.a0 = src; s.outh = outh; s.N = nelem; s.nblk = nelem / 1024;
}
static void slice_scat(Slice& s, const int* dst, const int* src, int* cur, int* colout, int E) {
  s.kind = K_SCAT; s.rp = dst; s.col = src; s.out = (float*)cur;
  s.outh = (unsigned short*)colout; s.N = E; s.nblk = (E + 255) / 256;
}
static int pack_blocks(const Pack& p, int n) {
  int t = 0;
  for (int i = 0; i < n; ++i) t += p.s[i].nblk;
  return t;
}

extern "C" void kernel_launch(void* const* d_in, const int* in_sizes, int n_in,
                              void* d_out, int out_size, void* d_ws, size_t ws_size,
                              hipStream_t stream) {
  (void)n_in; (void)out_size; (void)ws_size;
  const float* u  = (const float*)d_in[0];
  const float* it = (const float*)d_in[1];
  const float* g1r_Ws = (const float*)d_in[2];  const float* g1r_bs = (const float*)d_in[3];
  const float* g1r_Wd = (const float*)d_in[4];  const float* g1r_bd = (const float*)d_in[5];
  const float* g1r_a  = (const float*)d_in[6];
  const float* g1d_Ws = (const float*)d_in[7];  const float* g1d_bs = (const float*)d_in[8];
  const float* g1d_Wd = (const float*)d_in[9];  const float* g1d_bd = (const float*)d_in[10];
  const float* g1d_a  = (const float*)d_in[11];
  const float* g2d_Ws = (const float*)d_in[12]; const float* g2d_bs = (const float*)d_in[13];
  const float* g2d_Wd = (const float*)d_in[14]; const float* g2d_bd = (const float*)d_in[15];
  const float* g2d_a  = (const float*)d_in[16];
  const float* g2f_Ws = (const float*)d_in[17]; const float* g2f_bs = (const float*)d_in[18];
  const float* g2f_Wd = (const float*)d_in[19]; const float* g2f_bd = (const float*)d_in[20];
  const float* g2f_a  = (const float*)d_in[21];
  const float* spec_Ws = (const float*)d_in[22]; const float* spec_bs = (const float*)d_in[23];
  const float* spec_Wd = (const float*)d_in[24]; const float* spec_bd = (const float*)d_in[25];
  const float* spec_a  = (const float*)d_in[26];
  const float* cheb_W = (const float*)d_in[27]; const float* cheb_b = (const float*)d_in[28];
  const float* out_W  = (const float*)d_in[29]; const float* out_b  = (const float*)d_in[30];
  const float* mc_W   = (const float*)d_in[31]; const float* mc_b   = (const float*)d_in[32];
  const float* ms_W   = (const float*)d_in[33]; const float* ms_b   = (const float*)d_in[34];
  const float* pp_W   = (const float*)d_in[35]; const float* pp_b   = (const float*)d_in[36];
  const float* ps_W   = (const float*)d_in[37]; const float* ps_b   = (const float*)d_in[38];
  const float* lambda_max = (const float*)d_in[39];
  const int* rate_src   = (const int*)d_in[40];
  const int* rate_dst   = (const int*)d_in[41];
  const int* friend_src = (const int*)d_in[42];
  const int* friend_dst = (const int*)d_in[43];

  const int NU = in_sizes[0] / D;        // 8192
  const int NI = in_sizes[1] / D;        // 8192
  const int ER = in_sizes[40];           // 524288
  const int EF = in_sizes[42];           // 262144
  const size_t NF = (size_t)NU * D;

  // ---- workspace carve ----
  float* p = (float*)d_ws;
  float* E1 = p; p += NF;  float* R1 = p; p += NF;
  float* E2 = p; p += NF;  float* R2 = p; p += NF;
  float* E3 = p; p += NF;  float* R3 = p; p += NF;
  float* E4 = p; p += NF;  float* R4 = p; p += NF;
  float* E5 = p; p += NF;  float* R5 = p; p += NF;
  float* X1 = p; p += NF;  float* X2 = p; p += NF;
  float* H1 = p; p += NF;  float* H2 = p; p += NF;
  float* CH = p; p += NF;  float* IINF = p; p += NF;
  float* SOC = p; p += NF; float* HUP = p; p += NF;
  unsigned short* Uhl = (unsigned short*)p; p += NF;
  unsigned short* Ihl = (unsigned short*)p; p += NF;
  unsigned short* Phl = (unsigned short*)p; p += NF;
  unsigned short* Shl = (unsigned short*)p; p += NF;
  float* nrm = p; p += NU;
  int* ip     = (int*)p;
  int* rp_Rd  = ip;
  int* rp_Rs  = rp_Rd + (NI + 1);
  int* rp_Fd  = rp_Rs + (NU + 1);
  int* cur_Rd = rp_Fd + (NU + 1);
  int* cur_Rs = cur_Rd + NI;
  int* cur_Fd = cur_Rs + NU;
  int* col_Rd = cur_Fd + NU;
  int* col_Rs = col_Rd + ER;
  int* col_Fd = col_Rs + ER;
  int* deg3   = col_Fd + EF;
  int* degRd = deg3;
  int* degRs = deg3 + NI;
  int* degFd = deg3 + NI + NU;

  dim3 b256(256);

  // ---- CSR: zero -> count -> scan ----
  hipMemsetAsync(deg3, 0, (size_t)(NI + NU + NU) * sizeof(int), stream);
  int totE = 2 * ER + EF;
  count3_k<<<(totE + 255) / 256, b256, 0, stream>>>(rate_src, rate_dst, friend_dst, ER, EF,
                                                    degRd, degRs, degFd);
  scan3_k<<<3, 1024, 0, stream>>>(deg3, NI, NU, rp_Rd, rp_Rs, rp_Fd, cur_Rd, cur_Rs, cur_Fd, nrm);

  // ---- N4: scatter x3 + layer-1 transforms + u/it splits ----
  {
    Pack pk = {};
    slice_scat(pk.s[0], rate_dst, rate_src, cur_Rd, col_Rd, ER);
    slice_scat(pk.s[1], rate_src, rate_dst, cur_Rs, col_Rs, ER);
    slice_scat(pk.s[2], friend_dst, friend_src, cur_Fd, col_Fd, EF);
    slice_gemm(pk.s[3], u,  nullptr, nullptr, 1, g1r_Ws, g1r_bs, E1, NU);
    slice_gemm(pk.s[4], it, nullptr, nullptr, 1, g1r_Wd, g1r_bd, R1, NI);
    slice_gemm(pk.s[5], it, nullptr, nullptr, 1, g1d_Ws, g1d_bs, E2, NI);
    slice_gemm(pk.s[6], u,  nullptr, nullptr, 1, g1d_Wd, g1d_bd, R2, NU);
    slice_split(pk.s[7], u,  Uhl, (int)NF);
    slice_split(pk.s[8], it, Ihl, (int)NF);
    mega_k<<<pack_blocks(pk, 9), b256, 0, stream>>>(pk, 9);
  }
  // ---- N5: GAT1, GAT2, cheb X1 ----
  {
    Pack pk = {};
    slice_gat(pk.s[0], E1, R1, g1r_a, rp_Rd, col_Rd, H1, NI);
    slice_gat(pk.s[1], E2, R2, g1d_a, rp_Rs, col_Rs, H2, NU);
    slice_cheb(pk.s[2], u, nullptr, nrm, lambda_max, rp_Fd, col_Fd, X1, NU, 1);
    mega_k<<<pack_blocks(pk, 3), b256, 0, stream>>>(pk, 3);
  }
  // ---- N6: layer-2 transforms + cheb X2 ----
  {
    Pack pk = {};
    slice_gemm(pk.s[0], H1, nullptr, nullptr, 1, g2d_Ws, g2d_bs, E3, NI);
    slice_gemm(pk.s[1], u,  nullptr, nullptr, 1, g2d_Wd, g2d_bd, R3, NU);
    slice_gemm(pk.s[2], H2, nullptr, nullptr, 1, g2f_Ws, g2f_bs, E4, NU);
    slice_gemm(pk.s[3], u,  nullptr, nullptr, 1, g2f_Wd, g2f_bd, R4, NU);
    slice_cheb(pk.s[4], X1, u, nrm, lambda_max, rp_Fd, col_Fd, X2, NU, 2);
    mega_k<<<pack_blocks(pk, 5), b256, 0, stream>>>(pk, 5);
  }
  // ---- N7: GAT3, GAT4, ch gemm ----
  {
    Pack pk = {};
    slice_gat(pk.s[0], E3, R3, g2d_a, rp_Rs, col_Rs, IINF, NU);
    slice_gat(pk.s[1], E4, R4, g2f_a, rp_Fd, col_Fd, SOC, NU);
    slice_gemm(pk.s[2], u, X1, X2, 3, cheb_W, cheb_b, CH, NU);
    mega_k<<<pack_blocks(pk, 3), b256, 0, stream>>>(pk, 3);
  }
  // ---- N8: GEMM2 (user_pref -> h_uP) + spec transforms ----
  {
    Pack pk = {};
    pk.s[0].kind = K_GEMM2;
    pk.s[0].a0 = IINF; pk.s[0].a1 = SOC; pk.s[0].nparts = 2;
    pk.s[0].w = out_W; pk.s[0].b = out_b;
    pk.s[0].a2 = u; pk.s[0].w2 = mc_W; pk.s[0].b2 = mc_b;
    pk.s[0].out = HUP; pk.s[0].N = NU; pk.s[0].nblk = NU / 16;
    slice_gemm(pk.s[1], CH, nullptr, nullptr, 1, spec_Ws, spec_bs, E5, NU);
    slice_gemm(pk.s[2], CH, nullptr, nullptr, 1, spec_Wd, spec_bd, R5, NU);
    mega_k<<<pack_blocks(pk, 3), b256, 0, stream>>>(pk, 3);
  }
  // ---- N9: fused tail ----
  tail_k<<<NU / 8, b256, 0, stream>>>(E5, R5, spec_a, rp_Fd, col_Fd, u, HUP,
                                      ms_W, ms_b, pp_W, pp_b, ps_W, ps_b, Phl, Shl, NU);
  // ---- N10: finals ----
  float* outf = (float*)d_out;
  mfma_abt_k<<<dim3(NI / 128, NU / 128, 2), b256, 0, stream>>>(
      Phl, Ihl, Shl, Uhl, outf, outf + (size_t)NU * NI, NI, NF);
}